// Round 5
// baseline (424.045 us; speedup 1.0000x reference)
//
#include <hip/hip_runtime.h>
#include <hip/hip_fp16.h>
#include <hip/hip_bf16.h>
#include <math.h>

typedef unsigned short u16;
typedef __attribute__((ext_vector_type(8))) short bf16x8;
typedef __attribute__((ext_vector_type(8))) unsigned short u16x8;
typedef __attribute__((ext_vector_type(4))) unsigned short u16x4;
typedef __attribute__((ext_vector_type(4))) float f32x4;

static constexpr float NEGF = -1e30f;
static constexpr float CLAMPF = 3.8918202981106265f; // -log(1/0.98 - 1)
static constexpr float SCALEF = 0.125f;              // 1/sqrt(64)
static constexpr float ASCALE = 16384.f;             // 2^14 alpha storage scale

__device__ __forceinline__ u16 f2bf(float x) {
    __hip_bfloat16 h = __float2bfloat16(x);
    return *reinterpret_cast<u16*>(&h);
}
__device__ __forceinline__ float bf2f(u16 b) {
    unsigned int u = ((unsigned int)b) << 16;
    return __uint_as_float(u);
}

// ---------------------------------------------------------------------------
// f32 -> bf16 conversion (vectorized 4/thread)
// ---------------------------------------------------------------------------
__global__ __launch_bounds__(256)
void cvt_f32_bf16_k(const float* __restrict__ src, u16* __restrict__ dst, int n4)
{
    int i = blockIdx.x * 256 + threadIdx.x;
    if (i < n4) {
        float4 v = ((const float4*)src)[i];
        u16x4 o; o.x = f2bf(v.x); o.y = f2bf(v.y); o.z = f2bf(v.z); o.w = f2bf(v.w);
        ((u16x4*)dst)[i] = o;
    }
}

// ---------------------------------------------------------------------------
// bf16 MFMA GEMM, NT form: C[m][n] = sum_k A[m][k]*B[n][k]  (+ epilogue)
// Tile TM x TN, BK=64, 256 threads = 4 waves in 2x2 grid, mfma_f32_16x16x32_bf16.
// EPI: 0=bf16(+opt bias), 1=fp16 sigmoid(CLAMP*tanh(x)) (fast rcp), 3=f32+bias,
//      4=bf16 V-transpose store (VT[(b*16+h)*64+d][k]) + bias
// ---------------------------------------------------------------------------
template<int TM, int TN, int EPI>
__global__ __launch_bounds__(256)
void mfma_nt(const u16* __restrict__ Ag, const u16* __restrict__ Bg,
             void* __restrict__ Cg, const float* __restrict__ bias,
             int K, int lda, int ldb, int ldc,
             long sAb, long sAh, long sBb, long sBh, long sCb, long sCh,
             int hdiv)
{
    __shared__ u16 As[TM * 64];
    __shared__ u16 Bs[TN * 64];

    int z = blockIdx.z;
    int b = z / hdiv, h = z % hdiv;
    const u16* A = Ag + (long)b * sAb + (long)h * sAh;
    const u16* B = Bg + (long)b * sBb + (long)h * sBh;

    int tid = threadIdx.x;
    int bm = blockIdx.y * TM, bn = blockIdx.x * TN;

    constexpr int AC = TM / 32;
    constexpr int BC = TN / 32;
    int srow = tid >> 3;          // 0..31
    int scol = (tid & 7) * 8;     // 0..56

    int wid = tid >> 6, lane = tid & 63;
    int wr = wid >> 1, wc = wid & 1;
    constexpr int MI = TM / 32;
    constexpr int NI = TN / 32;
    int arow0 = wr * (TM / 2) + (lane & 15);
    int bcol0 = wc * (TN / 2) + (lane & 15);
    int koff = (lane >> 4) * 8;

    f32x4 acc[MI][NI];
#pragma unroll
    for (int i = 0; i < MI; ++i)
#pragma unroll
        for (int j = 0; j < NI; ++j) acc[i][j] = (f32x4){0.f, 0.f, 0.f, 0.f};

    for (int kt = 0; kt < K; kt += 64) {
        u16x8 av[AC], bv[BC];
#pragma unroll
        for (int c = 0; c < AC; ++c)
            av[c] = *(const u16x8*)(A + (long)(bm + srow + 32 * c) * lda + kt + scol);
#pragma unroll
        for (int c = 0; c < BC; ++c)
            bv[c] = *(const u16x8*)(B + (long)(bn + srow + 32 * c) * ldb + kt + scol);
        __syncthreads();
#pragma unroll
        for (int c = 0; c < AC; ++c)
            *(u16x8*)&As[(srow + 32 * c) * 64 + scol] = av[c];
#pragma unroll
        for (int c = 0; c < BC; ++c)
            *(u16x8*)&Bs[(srow + 32 * c) * 64 + scol] = bv[c];
        __syncthreads();

#pragma unroll
        for (int ks = 0; ks < 2; ++ks) {
            bf16x8 af[MI], bfr[NI];
#pragma unroll
            for (int mi = 0; mi < MI; ++mi)
                af[mi] = *(const bf16x8*)&As[(arow0 + 16 * mi) * 64 + ks * 32 + koff];
#pragma unroll
            for (int ni = 0; ni < NI; ++ni)
                bfr[ni] = *(const bf16x8*)&Bs[(bcol0 + 16 * ni) * 64 + ks * 32 + koff];
#pragma unroll
            for (int mi = 0; mi < MI; ++mi)
#pragma unroll
                for (int ni = 0; ni < NI; ++ni)
                    acc[mi][ni] = __builtin_amdgcn_mfma_f32_16x16x32_bf16(
                        af[mi], bfr[ni], acc[mi][ni], 0, 0, 0);
        }
    }

    // Epilogue
    int rbase = bm + wr * (TM / 2) + (lane >> 4) * 4;
    int cbase = bn + wc * (TN / 2) + (lane & 15);
#pragma unroll
    for (int mi = 0; mi < MI; ++mi) {
#pragma unroll
        for (int ni = 0; ni < NI; ++ni) {
            int m0 = rbase + 16 * mi;
            int n = cbase + 16 * ni;
            if constexpr (EPI == 0) {
                u16* C = (u16*)Cg + (long)b * sCb + (long)h * sCh;
                float bvv = bias ? bias[n] : 0.f;
#pragma unroll
                for (int r = 0; r < 4; ++r)
                    C[(long)(m0 + r) * ldc + n] = f2bf(acc[mi][ni][r] + bvv);
            } else if constexpr (EPI == 1) {
                __half* C = (__half*)Cg + (long)b * sCb + (long)h * sCh;
#pragma unroll
                for (int r = 0; r < 4; ++r) {
                    float x = acc[mi][ni][r];
                    float e2 = __expf(2.f * x);
                    float tv = CLAMPF - (2.f * CLAMPF) * __builtin_amdgcn_rcpf(e2 + 1.f);
                    float pv = __builtin_amdgcn_rcpf(1.f + __expf(-tv));
                    C[(long)(m0 + r) * ldc + n] = __float2half(pv);
                }
            } else if constexpr (EPI == 3) {
                float* C = (float*)Cg + (long)b * sCb + (long)h * sCh;
                float bvv = bias[n];
#pragma unroll
                for (int r = 0; r < 4; ++r)
                    C[(long)(m0 + r) * ldc + n] = acc[mi][ni][r] + bvv;
            } else { // EPI == 4: VT[(b16h)*64 + d][k] = V[m=b*1024+k][n=h*64+d]
                u16* C = (u16*)Cg;
                float bvv = bias[n];
                long vaddr = ((long)((m0 >> 10) * 16 + (n >> 6)) * 64 + (n & 63)) * 1024
                             + (m0 & 1023);
                u16x4 pk;
                pk.x = f2bf(acc[mi][ni][0] + bvv);
                pk.y = f2bf(acc[mi][ni][1] + bvv);
                pk.z = f2bf(acc[mi][ni][2] + bvv);
                pk.w = f2bf(acc[mi][ni][3] + bvv);
                *(u16x4*)(C + vaddr) = pk;
            }
        }
    }
}

// ---------------------------------------------------------------------------
// Monotonic DP, LINEAR probability domain (scaled by 2^14; mass-conserving so
// no rescaling needed). One WAVE per (b,h) slice; lane owns 16 contiguous k.
// a_new[i] = a[i]*p[i] + a[i-1]*(1-p[i-1]); shift via shfl_up. No LDS/barrier.
// Chunked over q (alpha cols [q0, q0+256)); f32 state carried in STATE.
// ---------------------------------------------------------------------------
struct pv16 { uint4 lo, hi; };

__device__ __forceinline__ pv16 dp_load(const __half* p, int col, int i0) {
    pv16 r;
    const uint4* src = (const uint4*)(p + (long)col * 1024 + i0);
    r.lo = src[0]; r.hi = src[1];
    return r;
}

#define DP_STEP(PC, J) do { \
    const __half2* hp = (const __half2*)&(PC); \
    float t[16], u[16]; \
    _Pragma("unroll") \
    for (int r8 = 0; r8 < 8; ++r8) { \
        float2 f = __half22float2(hp[r8]); \
        t[2 * r8]     = a[2 * r8]     * f.x; \
        t[2 * r8 + 1] = a[2 * r8 + 1] * f.y; \
    } \
    _Pragma("unroll") \
    for (int r = 0; r < 16; ++r) u[r] = a[r] - t[r]; \
    float up = __shfl_up(u[15], 1, 64); \
    if (lane == 0) up = 0.f; \
    a[0] = t[0] + up; \
    _Pragma("unroll") \
    for (int r = 1; r < 16; ++r) a[r] = t[r] + u[r - 1]; \
    uint4 o0, o1; \
    { __half2 h0 = __floats2half2_rn(a[0], a[1]),  h1 = __floats2half2_rn(a[2], a[3]); \
      __half2 h2 = __floats2half2_rn(a[4], a[5]),  h3 = __floats2half2_rn(a[6], a[7]); \
      o0.x = *(unsigned*)&h0; o0.y = *(unsigned*)&h1; o0.z = *(unsigned*)&h2; o0.w = *(unsigned*)&h3; \
      __half2 h4 = __floats2half2_rn(a[8], a[9]),  h5 = __floats2half2_rn(a[10], a[11]); \
      __half2 h6 = __floats2half2_rn(a[12], a[13]), h7 = __floats2half2_rn(a[14], a[15]); \
      o1.x = *(unsigned*)&h4; o1.y = *(unsigned*)&h5; o1.z = *(unsigned*)&h6; o1.w = *(unsigned*)&h7; } \
    uint4* dst = (uint4*)(al + (long)((J) - q0) * 1024 + i0); \
    dst[0] = o0; dst[1] = o1; \
} while (0)

__global__ __launch_bounds__(64)
void mono_dp_k(const __half* __restrict__ P, __half* __restrict__ AL,
               float* __restrict__ STATE, int q0)
{
    int n = blockIdx.x;
    int lane = threadIdx.x;                 // 0..63
    const __half* p = P + (long)n * 524288; // (512,1024) sigmoid probs
    __half* al = AL + (long)n * 262144;     // (256,1024) alpha chunk (scaled lin)
    float* stt = STATE + (long)n * 1024;
    int i0 = lane * 16;

    float a[16];
    if (q0 == 0) {
#pragma unroll
        for (int r = 0; r < 16; ++r) a[r] = 0.f;
        if (lane == 0) a[0] = ASCALE;
        // alpha column 0 = init distribution
        uint4 o0, o1;
        __half2 h0 = __floats2half2_rn(a[0], a[1]), h1 = __floats2half2_rn(a[2], a[3]);
        __half2 h2 = __floats2half2_rn(a[4], a[5]), h3 = __floats2half2_rn(a[6], a[7]);
        o0.x = *(unsigned*)&h0; o0.y = *(unsigned*)&h1; o0.z = *(unsigned*)&h2; o0.w = *(unsigned*)&h3;
        __half2 h4 = __floats2half2_rn(a[8], a[9]), h5 = __floats2half2_rn(a[10], a[11]);
        __half2 h6 = __floats2half2_rn(a[12], a[13]), h7 = __floats2half2_rn(a[14], a[15]);
        o1.x = *(unsigned*)&h4; o1.y = *(unsigned*)&h5; o1.z = *(unsigned*)&h6; o1.w = *(unsigned*)&h7;
        uint4* dst = (uint4*)(al + i0);
        dst[0] = o0; dst[1] = o1;
    } else {
#pragma unroll
        for (int r4 = 0; r4 < 4; ++r4) {
            float4 s = *(const float4*)(stt + i0 + 4 * r4);
            a[4 * r4 + 0] = s.x; a[4 * r4 + 1] = s.y;
            a[4 * r4 + 2] = s.z; a[4 * r4 + 3] = s.w;
        }
    }

    int jbeg = (q0 == 0) ? 1 : q0;
    int jend = q0 + 256;

    // depth-2 prefetch with statically named registers
    int j = jbeg;
    pv16 pA = dp_load(p, j - 1, i0);
    pv16 pB = dp_load(p, j, i0);
    while (j + 1 < jend) {
        DP_STEP(pA, j);
        pA = dp_load(p, min(j + 1, 511), i0);
        DP_STEP(pB, j + 1);
        pB = dp_load(p, min(j + 2, 511), i0);
        j += 2;
    }
    if (j < jend) DP_STEP(pA, j);

#pragma unroll
    for (int r4 = 0; r4 < 4; ++r4) {
        float4 s;
        s.x = a[4 * r4 + 0]; s.y = a[4 * r4 + 1];
        s.z = a[4 * r4 + 2]; s.w = a[4 * r4 + 3];
        *(float4*)(stt + i0 + 4 * r4) = s;
    }
}

// ---------------------------------------------------------------------------
// Fused attention: reg scores (S^T = K.Q^T via MFMA) + alpha-weighted softmax
// + PV, one block per (n, 64 q-rows). 4 waves, each owns 16 q-rows; wave-
// private LDS only (alpha tile + swizzled w tile) -> NO barriers.
// Two passes over k: pass1 row-max of raw scores; pass2 recompute S,
// w = alpha * exp(SCALE*(s - m)), accumulate l and O (unnormalized), scale by
// 1/l at the end. Q-frags hoisted; K/V frags read from global (L2-hot).
// ---------------------------------------------------------------------------
__global__ __launch_bounds__(256)
void fused_attn_k(const u16* __restrict__ XQAQ, const u16* __restrict__ XK,
                  const u16* __restrict__ VT, const __half* __restrict__ AL,
                  u16* __restrict__ XO, int c0)
{
    __shared__ u16 lds[4][4224];   // per wave: alpha 16x136 (2176) + w 16x128 (2048)
    int n = blockIdx.z; int b = n >> 4; int h = n & 15;
    int tid = threadIdx.x; int wave = tid >> 6; int lane = tid & 63;
    int l15 = lane & 15, l4 = lane >> 4;
    int qc = blockIdx.x * 64 + wave * 16;   // q base within chunk [0,256)
    int qg = c0 + qc;                        // q base within 512
    u16* alds = lds[wave];
    u16* wlds = lds[wave] + 2176;
    int swz = (l15 & 7) << 3;                // XOR swizzle (halfs) for w tile

    // Q B-frags (col=q=l15), hoisted for all k-tiles and both passes
    const u16* qbase = XQAQ + (long)(b * 512 + qg + l15) * 2048 + 1024 + h * 64 + l4 * 8;
    bf16x8 qf0 = *(const bf16x8*)(qbase);
    bf16x8 qf1 = *(const bf16x8*)(qbase + 32);

    long kstride = 1024;
    const u16* kbase0 = XK + (long)(b * 1024 + l15) * 1024 + h * 64 + l4 * 8;

    // ---- pass 1: raw row max (per lane: q = l15) ----
    float mraw = -3.4e38f;
    for (int kt = 0; kt < 8; ++kt) {
#pragma unroll
        for (int kf = 0; kf < 8; ++kf) {
            const u16* kb = kbase0 + (long)(kt * 128 + kf * 16) * kstride;
            bf16x8 k0 = *(const bf16x8*)kb;
            bf16x8 k1 = *(const bf16x8*)(kb + 32);
            f32x4 acc = (f32x4){0.f, 0.f, 0.f, 0.f};
            acc = __builtin_amdgcn_mfma_f32_16x16x32_bf16(k0, qf0, acc, 0, 0, 0);
            acc = __builtin_amdgcn_mfma_f32_16x16x32_bf16(k1, qf1, acc, 0, 0, 0);
            mraw = fmaxf(mraw, fmaxf(fmaxf(acc[0], acc[1]), fmaxf(acc[2], acc[3])));
        }
    }
    mraw = fmaxf(mraw, __shfl_xor(mraw, 16, 64));
    mraw = fmaxf(mraw, __shfl_xor(mraw, 32, 64));
    float negm = -mraw * SCALEF;

    // ---- pass 2: w = a*exp(s*SCALE - m*SCALE); accumulate l and O ----
    f32x4 o[4];
#pragma unroll
    for (int df = 0; df < 4; ++df) o[df] = (f32x4){0.f, 0.f, 0.f, 0.f};
    float lsum = 0.f;

    const __half* albase = AL + (long)(n * 256 + qc + l15) * 1024 + l4 * 32;

    for (int kt = 0; kt < 8; ++kt) {
        // stage alpha tile 16q x 128k (wave-private; lane: row l15, 64B)
        {
            const u16* ga = (const u16*)(albase + kt * 128);
            u16x8 a0 = *(const u16x8*)(ga + 0);
            u16x8 a1 = *(const u16x8*)(ga + 8);
            u16x8 a2 = *(const u16x8*)(ga + 16);
            u16x8 a3 = *(const u16x8*)(ga + 24);
            u16* wb = &alds[l15 * 136 + l4 * 32];
            *(u16x8*)(wb + 0) = a0; *(u16x8*)(wb + 8) = a1;
            *(u16x8*)(wb + 16) = a2; *(u16x8*)(wb + 24) = a3;
        }
#pragma unroll
        for (int kf = 0; kf < 8; ++kf) {
            const u16* kb = kbase0 + (long)(kt * 128 + kf * 16) * kstride;
            bf16x8 k0 = *(const bf16x8*)kb;
            bf16x8 k1 = *(const bf16x8*)(kb + 32);
            f32x4 acc = (f32x4){0.f, 0.f, 0.f, 0.f};
            acc = __builtin_amdgcn_mfma_f32_16x16x32_bf16(k0, qf0, acc, 0, 0, 0);
            acc = __builtin_amdgcn_mfma_f32_16x16x32_bf16(k1, qf1, acc, 0, 0, 0);
            u16x4 wp;
#pragma unroll
            for (int r = 0; r < 4; ++r) {
                float av = __half2float(((const __half*)alds)[l15 * 136 + kf * 16 + l4 * 4 + r]);
                float wv = av * __expf(fmaf(acc[r], SCALEF, negm));
                lsum += wv;
                wp[r] = f2bf(wv);
            }
            *(u16x4*)&wlds[(l15 * 128 + kf * 16 + l4 * 4) ^ swz] = wp;
        }
        // PV over this 128-k tile (A = w from swizzled LDS, B = VT from global)
#pragma unroll
        for (int ks2 = 0; ks2 < 4; ++ks2) {
            bf16x8 wf = *(const bf16x8*)&wlds[(l15 * 128 + ks2 * 32 + l4 * 8) ^ swz];
#pragma unroll
            for (int df = 0; df < 4; ++df) {
                const u16* vb = VT + (long)(n * 64 + df * 16 + l15) * 1024
                                + kt * 128 + ks2 * 32 + l4 * 8;
                bf16x8 vf = *(const bf16x8*)vb;
                o[df] = __builtin_amdgcn_mfma_f32_16x16x32_bf16(wf, vf, o[df], 0, 0, 0);
            }
        }
    }

    // l reduce (per q=l15), redistribute to O rows (q=(l>>4)*4+r), store
    lsum += __shfl_xor(lsum, 16, 64);
    lsum += __shfl_xor(lsum, 32, 64);
    float linv = __builtin_amdgcn_rcpf(lsum);
#pragma unroll
    for (int r = 0; r < 4; ++r) {
        float li = __shfl(linv, l4 * 4 + r, 64);
        long orow = (long)(b * 512 + qg + l4 * 4 + r);
#pragma unroll
        for (int df = 0; df < 4; ++df)
            XO[orow * 1024 + h * 64 + df * 16 + l15] = f2bf(o[df][r] * li);
    }
}

// ---------------------------------------------------------------------------
extern "C" void kernel_launch(void* const* d_in, const int* in_sizes, int n_in,
                              void* d_out, int out_size, void* d_ws, size_t ws_size,
                              hipStream_t stream)
{
    const float* q   = (const float*)d_in[0];
    const float* key = (const float*)d_in[1];
    const float* val = (const float*)d_in[2];
    const float* W   = (const float*)d_in[3];
    const float* ipb = (const float*)d_in[4];
    const float* ow  = (const float*)d_in[5];
    const float* ob  = (const float*)d_in[6];
    float* out = (float*)d_out;
    char* w = (char*)d_ws;

    // Workspace layout (bytes). Total 132,382,720 B (same as passing r3/r4).
    __half* PSIG   = (__half*)(w);                 // 64 MiB  (64,512,1024) fp16 sigmoid(phi)
    __half* ALPHAC = (__half*)(w + 67108864);      // 32 MiB  (64,256,1024) fp16 linear alpha
    float*  STATE  = (float*)(w + 100663296);      // 256 KiB (64,1024) f32
    u16*    XQAQ   = (u16*)(w + 100925440);        // 8 MiB   (2048,2048) bf16
    u16*    XK     = (u16*)(w + 109314048);        // 8 MiB   (4096,1024) bf16
    u16*    VT     = (u16*)(w + 117702656);        // 8 MiB   (64,64,1024) bf16
    u16*    XO     = (u16*)(w + 126091264);        // 4 MiB   (2048,1024) bf16
    u16*    OWBF   = (u16*)(w + 130285568);        // 2 MiB   (1024,1024) bf16
    // Overlays inside PSIG region (dead before phi GEMM writes):
    u16* QBF = (u16*)(w);                          // 4 MiB
    u16* KBF = (u16*)(w + 4194304);                // 8 MiB
    u16* VBF = (u16*)(w + 12582912);               // 8 MiB
    u16* WBF = (u16*)(w + 20971520);               // 8 MiB

    dim3 blk(256);

    // 0) f32 -> bf16 copies
    cvt_f32_bf16_k<<<dim3(2048), blk, 0, stream>>>(q, QBF, 524288);
    cvt_f32_bf16_k<<<dim3(4096), blk, 0, stream>>>(key, KBF, 1048576);
    cvt_f32_bf16_k<<<dim3(4096), blk, 0, stream>>>(val, VBF, 1048576);
    cvt_f32_bf16_k<<<dim3(4096), blk, 0, stream>>>(W, WBF, 1048576);
    cvt_f32_bf16_k<<<dim3(1024), blk, 0, stream>>>(ow, OWBF, 262144);

    // 1) XQAQ = q @ W[0:2048]^T + ipb[0:2048]  (cols 0..1023 = xqa, 1024.. = xq)
    mfma_nt<128, 128, 0><<<dim3(16, 16, 1), blk, 0, stream>>>(
        QBF, WBF, XQAQ, ipb, 1024, 1024, 1024, 2048, 0, 0, 0, 0, 0, 0, 1);
    // 2) XK = key @ W[2048:3072]^T + ipb[2048:3072]
    mfma_nt<128, 128, 0><<<dim3(8, 32, 1), blk, 0, stream>>>(
        KBF, WBF + 2097152, XK, ipb + 2048, 1024, 1024, 1024, 1024, 0, 0, 0, 0, 0, 0, 1);
    // 3) VT = transpose(val @ W[3072:4096]^T + ipb[3072:4096])
    mfma_nt<128, 128, 4><<<dim3(8, 32, 1), blk, 0, stream>>>(
        VBF, WBF + 3145728, VT, ipb + 3072, 1024, 1024, 1024, 0, 0, 0, 0, 0, 0, 0, 1);
    // 4) PSIG[n][q][k] = sigmoid(CLAMP * tanh(xqa_q . xk_k)) -> fp16
    mfma_nt<128, 128, 1><<<dim3(8, 4, 64), blk, 0, stream>>>(
        XQAQ, XK, PSIG, nullptr, 64, 2048, 1024, 1024,
        512L * 2048, 64, 1024L * 1024, 64, 8388608L, 524288L, 16);

    // 5) two 256-q chunks: DP -> fused attention (scores+softmax+PV)
    for (int c = 0; c < 2; ++c) {
        mono_dp_k<<<dim3(64), dim3(64), 0, stream>>>(PSIG, ALPHAC, STATE, c * 256);
        fused_attn_k<<<dim3(4, 1, 64), blk, 0, stream>>>(
            XQAQ, XK, VT, ALPHAC, XO, c * 256);
    }

    // 6) out = XO @ ow^T + ob  (f32)
    mfma_nt<128, 128, 3><<<dim3(8, 16, 1), blk, 0, stream>>>(
        XO, OWBF, out, ob, 1024, 1024, 1024, 1024, 0, 0, 0, 0, 0, 0, 1);
}

// Round 6
// 345.217 us; speedup vs baseline: 1.2283x; 1.2283x over previous
//
#include <hip/hip_runtime.h>
#include <hip/hip_fp16.h>
#include <hip/hip_bf16.h>
#include <math.h>

typedef unsigned short u16;
typedef __attribute__((ext_vector_type(8))) short bf16x8;
typedef __attribute__((ext_vector_type(8))) unsigned short u16x8;
typedef __attribute__((ext_vector_type(4))) unsigned short u16x4;
typedef __attribute__((ext_vector_type(4))) float f32x4;

static constexpr float NEGF = -1e30f;
static constexpr float CLAMPF = 3.8918202981106265f; // -log(1/0.98 - 1)
static constexpr float SCALEF = 0.125f;              // 1/sqrt(64)
static constexpr float ASCALE = 16384.f;             // 2^14 alpha storage scale

__device__ __forceinline__ u16 f2bf(float x) {
    __hip_bfloat16 h = __float2bfloat16(x);
    return *reinterpret_cast<u16*>(&h);
}
__device__ __forceinline__ float bf2f(u16 b) {
    unsigned int u = ((unsigned int)b) << 16;
    return __uint_as_float(u);
}

// ---------------------------------------------------------------------------
// f32 -> bf16 conversion (vectorized 4/thread)
// ---------------------------------------------------------------------------
__global__ __launch_bounds__(256)
void cvt_f32_bf16_k(const float* __restrict__ src, u16* __restrict__ dst, int n4)
{
    int i = blockIdx.x * 256 + threadIdx.x;
    if (i < n4) {
        float4 v = ((const float4*)src)[i];
        u16x4 o; o.x = f2bf(v.x); o.y = f2bf(v.y); o.z = f2bf(v.z); o.w = f2bf(v.w);
        ((u16x4*)dst)[i] = o;
    }
}

// ---------------------------------------------------------------------------
// bf16 MFMA GEMM, NT form: C[m][n] = sum_k A[m][k]*B[n][k]  (+ epilogue)
// Tile TM x TN, BK=64, 256 threads = 4 waves in 2x2 grid, mfma_f32_16x16x32_bf16.
// EPI: 0=bf16(+opt bias), 1=fp16 sigmoid(CLAMP*tanh(x)) (fast rcp), 3=f32+bias,
//      4=bf16 V-transpose store (VT[(b*16+h)*64+d][k]) + bias
// ---------------------------------------------------------------------------
template<int TM, int TN, int EPI>
__global__ __launch_bounds__(256)
void mfma_nt(const u16* __restrict__ Ag, const u16* __restrict__ Bg,
             void* __restrict__ Cg, const float* __restrict__ bias,
             int K, int lda, int ldb, int ldc,
             long sAb, long sAh, long sBb, long sBh, long sCb, long sCh,
             int hdiv)
{
    __shared__ u16 As[TM * 64];
    __shared__ u16 Bs[TN * 64];

    int z = blockIdx.z;
    int b = z / hdiv, h = z % hdiv;
    const u16* A = Ag + (long)b * sAb + (long)h * sAh;
    const u16* B = Bg + (long)b * sBb + (long)h * sBh;

    int tid = threadIdx.x;
    int bm = blockIdx.y * TM, bn = blockIdx.x * TN;

    constexpr int AC = TM / 32;
    constexpr int BC = TN / 32;
    int srow = tid >> 3;          // 0..31
    int scol = (tid & 7) * 8;     // 0..56

    int wid = tid >> 6, lane = tid & 63;
    int wr = wid >> 1, wc = wid & 1;
    constexpr int MI = TM / 32;
    constexpr int NI = TN / 32;
    int arow0 = wr * (TM / 2) + (lane & 15);
    int bcol0 = wc * (TN / 2) + (lane & 15);
    int koff = (lane >> 4) * 8;

    f32x4 acc[MI][NI];
#pragma unroll
    for (int i = 0; i < MI; ++i)
#pragma unroll
        for (int j = 0; j < NI; ++j) acc[i][j] = (f32x4){0.f, 0.f, 0.f, 0.f};

    for (int kt = 0; kt < K; kt += 64) {
        u16x8 av[AC], bv[BC];
#pragma unroll
        for (int c = 0; c < AC; ++c)
            av[c] = *(const u16x8*)(A + (long)(bm + srow + 32 * c) * lda + kt + scol);
#pragma unroll
        for (int c = 0; c < BC; ++c)
            bv[c] = *(const u16x8*)(B + (long)(bn + srow + 32 * c) * ldb + kt + scol);
        __syncthreads();
#pragma unroll
        for (int c = 0; c < AC; ++c)
            *(u16x8*)&As[(srow + 32 * c) * 64 + scol] = av[c];
#pragma unroll
        for (int c = 0; c < BC; ++c)
            *(u16x8*)&Bs[(srow + 32 * c) * 64 + scol] = bv[c];
        __syncthreads();

#pragma unroll
        for (int ks = 0; ks < 2; ++ks) {
            bf16x8 af[MI], bfr[NI];
#pragma unroll
            for (int mi = 0; mi < MI; ++mi)
                af[mi] = *(const bf16x8*)&As[(arow0 + 16 * mi) * 64 + ks * 32 + koff];
#pragma unroll
            for (int ni = 0; ni < NI; ++ni)
                bfr[ni] = *(const bf16x8*)&Bs[(bcol0 + 16 * ni) * 64 + ks * 32 + koff];
#pragma unroll
            for (int mi = 0; mi < MI; ++mi)
#pragma unroll
                for (int ni = 0; ni < NI; ++ni)
                    acc[mi][ni] = __builtin_amdgcn_mfma_f32_16x16x32_bf16(
                        af[mi], bfr[ni], acc[mi][ni], 0, 0, 0);
        }
    }

    // Epilogue
    int rbase = bm + wr * (TM / 2) + (lane >> 4) * 4;
    int cbase = bn + wc * (TN / 2) + (lane & 15);
#pragma unroll
    for (int mi = 0; mi < MI; ++mi) {
#pragma unroll
        for (int ni = 0; ni < NI; ++ni) {
            int m0 = rbase + 16 * mi;
            int n = cbase + 16 * ni;
            if constexpr (EPI == 0) {
                u16* C = (u16*)Cg + (long)b * sCb + (long)h * sCh;
                float bvv = bias ? bias[n] : 0.f;
#pragma unroll
                for (int r = 0; r < 4; ++r)
                    C[(long)(m0 + r) * ldc + n] = f2bf(acc[mi][ni][r] + bvv);
            } else if constexpr (EPI == 1) {
                __half* C = (__half*)Cg + (long)b * sCb + (long)h * sCh;
#pragma unroll
                for (int r = 0; r < 4; ++r) {
                    float x = acc[mi][ni][r];
                    float e2 = __expf(2.f * x);
                    float tv = CLAMPF - (2.f * CLAMPF) * __builtin_amdgcn_rcpf(e2 + 1.f);
                    float pv = __builtin_amdgcn_rcpf(1.f + __expf(-tv));
                    C[(long)(m0 + r) * ldc + n] = __float2half(pv);
                }
            } else if constexpr (EPI == 3) {
                float* C = (float*)Cg + (long)b * sCb + (long)h * sCh;
                float bvv = bias[n];
#pragma unroll
                for (int r = 0; r < 4; ++r)
                    C[(long)(m0 + r) * ldc + n] = acc[mi][ni][r] + bvv;
            } else { // EPI == 4: VT[(b16h)*64 + d][k] = V[m=b*1024+k][n=h*64+d]
                u16* C = (u16*)Cg;
                float bvv = bias[n];
                long vaddr = ((long)((m0 >> 10) * 16 + (n >> 6)) * 64 + (n & 63)) * 1024
                             + (m0 & 1023);
                u16x4 pk;
                pk.x = f2bf(acc[mi][ni][0] + bvv);
                pk.y = f2bf(acc[mi][ni][1] + bvv);
                pk.z = f2bf(acc[mi][ni][2] + bvv);
                pk.w = f2bf(acc[mi][ni][3] + bvv);
                *(u16x4*)(C + vaddr) = pk;
            }
        }
    }
}

// ---------------------------------------------------------------------------
// Monotonic DP, LINEAR probability domain (scaled by 2^14; mass-conserving so
// no rescaling needed). One WAVE per (b,h) slice; lane owns 16 contiguous k.
// a_new[i] = a[i]*p[i] + a[i-1]*(1-p[i-1]); shift via shfl_up. No LDS/barrier.
// Chunked over q (alpha cols [q0, q0+256)); f32 state carried in STATE.
// ---------------------------------------------------------------------------
struct pv16 { uint4 lo, hi; };

__device__ __forceinline__ pv16 dp_load(const __half* p, int col, int i0) {
    pv16 r;
    const uint4* src = (const uint4*)(p + (long)col * 1024 + i0);
    r.lo = src[0]; r.hi = src[1];
    return r;
}

#define DP_STEP(PC, J) do { \
    const __half2* hp = (const __half2*)&(PC); \
    float t[16], u[16]; \
    _Pragma("unroll") \
    for (int r8 = 0; r8 < 8; ++r8) { \
        float2 f = __half22float2(hp[r8]); \
        t[2 * r8]     = a[2 * r8]     * f.x; \
        t[2 * r8 + 1] = a[2 * r8 + 1] * f.y; \
    } \
    _Pragma("unroll") \
    for (int r = 0; r < 16; ++r) u[r] = a[r] - t[r]; \
    float up = __shfl_up(u[15], 1, 64); \
    if (lane == 0) up = 0.f; \
    a[0] = t[0] + up; \
    _Pragma("unroll") \
    for (int r = 1; r < 16; ++r) a[r] = t[r] + u[r - 1]; \
    uint4 o0, o1; \
    { __half2 h0 = __floats2half2_rn(a[0], a[1]),  h1 = __floats2half2_rn(a[2], a[3]); \
      __half2 h2 = __floats2half2_rn(a[4], a[5]),  h3 = __floats2half2_rn(a[6], a[7]); \
      o0.x = *(unsigned*)&h0; o0.y = *(unsigned*)&h1; o0.z = *(unsigned*)&h2; o0.w = *(unsigned*)&h3; \
      __half2 h4 = __floats2half2_rn(a[8], a[9]),  h5 = __floats2half2_rn(a[10], a[11]); \
      __half2 h6 = __floats2half2_rn(a[12], a[13]), h7 = __floats2half2_rn(a[14], a[15]); \
      o1.x = *(unsigned*)&h4; o1.y = *(unsigned*)&h5; o1.z = *(unsigned*)&h6; o1.w = *(unsigned*)&h7; } \
    uint4* dst = (uint4*)(al + (long)((J) - q0) * 1024 + i0); \
    dst[0] = o0; dst[1] = o1; \
} while (0)

__global__ __launch_bounds__(64)
void mono_dp_k(const __half* __restrict__ P, __half* __restrict__ AL,
               float* __restrict__ STATE, int q0)
{
    int n = blockIdx.x;
    int lane = threadIdx.x;                 // 0..63
    const __half* p = P + (long)n * 524288; // (512,1024) sigmoid probs
    __half* al = AL + (long)n * 262144;     // (256,1024) alpha chunk (scaled lin)
    float* stt = STATE + (long)n * 1024;
    int i0 = lane * 16;

    float a[16];
    if (q0 == 0) {
#pragma unroll
        for (int r = 0; r < 16; ++r) a[r] = 0.f;
        if (lane == 0) a[0] = ASCALE;
        // alpha column 0 = init distribution
        uint4 o0, o1;
        __half2 h0 = __floats2half2_rn(a[0], a[1]), h1 = __floats2half2_rn(a[2], a[3]);
        __half2 h2 = __floats2half2_rn(a[4], a[5]), h3 = __floats2half2_rn(a[6], a[7]);
        o0.x = *(unsigned*)&h0; o0.y = *(unsigned*)&h1; o0.z = *(unsigned*)&h2; o0.w = *(unsigned*)&h3;
        __half2 h4 = __floats2half2_rn(a[8], a[9]), h5 = __floats2half2_rn(a[10], a[11]);
        __half2 h6 = __floats2half2_rn(a[12], a[13]), h7 = __floats2half2_rn(a[14], a[15]);
        o1.x = *(unsigned*)&h4; o1.y = *(unsigned*)&h5; o1.z = *(unsigned*)&h6; o1.w = *(unsigned*)&h7;
        uint4* dst = (uint4*)(al + i0);
        dst[0] = o0; dst[1] = o1;
    } else {
#pragma unroll
        for (int r4 = 0; r4 < 4; ++r4) {
            float4 s = *(const float4*)(stt + i0 + 4 * r4);
            a[4 * r4 + 0] = s.x; a[4 * r4 + 1] = s.y;
            a[4 * r4 + 2] = s.z; a[4 * r4 + 3] = s.w;
        }
    }

    int jbeg = (q0 == 0) ? 1 : q0;
    int jend = q0 + 256;

    // depth-2 prefetch with statically named registers
    int j = jbeg;
    pv16 pA = dp_load(p, j - 1, i0);
    pv16 pB = dp_load(p, j, i0);
    while (j + 1 < jend) {
        DP_STEP(pA, j);
        pA = dp_load(p, min(j + 1, 511), i0);
        DP_STEP(pB, j + 1);
        pB = dp_load(p, min(j + 2, 511), i0);
        j += 2;
    }
    if (j < jend) DP_STEP(pA, j);

#pragma unroll
    for (int r4 = 0; r4 < 4; ++r4) {
        float4 s;
        s.x = a[4 * r4 + 0]; s.y = a[4 * r4 + 1];
        s.z = a[4 * r4 + 2]; s.w = a[4 * r4 + 3];
        *(float4*)(stt + i0 + 4 * r4) = s;
    }
}

// ---------------------------------------------------------------------------
// Fused attention, single-pass online softmax with 4-way k-split.
// grid (64 n, 16 q-groups); block = 4 waves; wave w handles 16 q x 256 k
// (k in [w*256,(w+1)*256)). Per 128-k tile: scores via MFMA (swapped: lane's
// l15 = q), tile-max, online rescale, w = alpha*exp(SCALE*(s-m)) -> swizzled
// wave-private LDS -> PV MFMA. Partials (m,l,o) combined across waves in LDS.
// ---------------------------------------------------------------------------
__global__ __launch_bounds__(256, 4)
void fused_attn_k(const u16* __restrict__ XQAQ, const u16* __restrict__ XK,
                  const u16* __restrict__ VT, const __half* __restrict__ AL,
                  u16* __restrict__ XO, int c0)
{
    __shared__ u16 wtile[4][2048];     // per-wave 16q x 128k bf16 (swizzled)
    __shared__ float co[4][16][64];    // per-wave partial O (q, d)
    __shared__ float cml[4][2][16];    // per-wave m, l per q

    int n = blockIdx.x; int b = n >> 4, h = n & 15;
    int tid = threadIdx.x, wave = tid >> 6, lane = tid & 63;
    int l15 = lane & 15, l4 = lane >> 4;
    int qc = blockIdx.y * 16;          // q base within chunk [0,256)
    int qg = c0 + qc;                  // q base within 512
    u16* wlds = wtile[wave];
    int swz = (l15 & 7) << 3;

    // Q B-frags (col=q=l15), hoisted
    const u16* qbase = XQAQ + (long)(b * 512 + qg + l15) * 2048 + 1024 + h * 64 + l4 * 8;
    bf16x8 qf0 = *(const bf16x8*)(qbase);
    bf16x8 qf1 = *(const bf16x8*)(qbase + 32);

    const u16* kbase = XK + (long)(b * 1024 + wave * 256 + l15) * 1024 + h * 64 + l4 * 8;
    const __half* abase = AL + (long)(n * 256 + qc + l15) * 1024 + wave * 256 + l4 * 4;
    const u16* vbase = VT + (long)(n * 64 + l15) * 1024 + wave * 256 + l4 * 8;

    float m = -3.0e38f, lsum = 0.f;
    f32x4 o[4];
#pragma unroll
    for (int df = 0; df < 4; ++df) o[df] = (f32x4){0.f, 0.f, 0.f, 0.f};

    for (int kt = 0; kt < 2; ++kt) {
        // alpha regs for this tile (q=l15, k = kt*128 + kf*16 + l4*4 + r)
        uint2 areg[8];
#pragma unroll
        for (int kf = 0; kf < 8; ++kf)
            areg[kf] = *(const uint2*)(abase + kt * 128 + kf * 16);

        // scores: s[kf][r] for q=l15, k = kt*128 + kf*16 + l4*4 + r
        f32x4 s[8];
#pragma unroll
        for (int kf = 0; kf < 8; ++kf) {
            const u16* kb = kbase + (long)(kt * 128 + kf * 16) * 1024;
            bf16x8 k0 = *(const bf16x8*)kb;
            bf16x8 k1 = *(const bf16x8*)(kb + 32);
            f32x4 acc = (f32x4){0.f, 0.f, 0.f, 0.f};
            acc = __builtin_amdgcn_mfma_f32_16x16x32_bf16(k0, qf0, acc, 0, 0, 0);
            acc = __builtin_amdgcn_mfma_f32_16x16x32_bf16(k1, qf1, acc, 0, 0, 0);
            s[kf] = acc;
        }

        // tile max per q (in-lane over 32 vals, then across l4 groups)
        float mt = -3.0e38f;
#pragma unroll
        for (int kf = 0; kf < 8; ++kf)
            mt = fmaxf(mt, fmaxf(fmaxf(s[kf][0], s[kf][1]), fmaxf(s[kf][2], s[kf][3])));
        mt = fmaxf(mt, __shfl_xor(mt, 16, 64));
        mt = fmaxf(mt, __shfl_xor(mt, 32, 64));

        float mn = fmaxf(m, mt);
        float f = __expf((m - mn) * SCALEF);
        m = mn;
        float negm = -mn * SCALEF;
        lsum *= f;
        // rescale o rows (q = l4*4 + r needs f from lane l4*4+r)
        float fr0 = __shfl(f, l4 * 4 + 0, 64);
        float fr1 = __shfl(f, l4 * 4 + 1, 64);
        float fr2 = __shfl(f, l4 * 4 + 2, 64);
        float fr3 = __shfl(f, l4 * 4 + 3, 64);
#pragma unroll
        for (int df = 0; df < 4; ++df) {
            o[df][0] *= fr0; o[df][1] *= fr1; o[df][2] *= fr2; o[df][3] *= fr3;
        }

        // w = alpha * exp(SCALE*(s - m)), accumulate l, store swizzled LDS
#pragma unroll
        for (int kf = 0; kf < 8; ++kf) {
            float2 a01 = __half22float2(*(__half2*)&areg[kf].x);
            float2 a23 = __half22float2(*(__half2*)&areg[kf].y);
            float w0 = a01.x * __expf(fmaf(s[kf][0], SCALEF, negm));
            float w1 = a01.y * __expf(fmaf(s[kf][1], SCALEF, negm));
            float w2 = a23.x * __expf(fmaf(s[kf][2], SCALEF, negm));
            float w3 = a23.y * __expf(fmaf(s[kf][3], SCALEF, negm));
            lsum += (w0 + w1) + (w2 + w3);
            u16x4 wp; wp.x = f2bf(w0); wp.y = f2bf(w1); wp.z = f2bf(w2); wp.w = f2bf(w3);
            *(u16x4*)&wlds[(l15 * 128 + kf * 16 + l4 * 4) ^ swz] = wp;
        }

        // PV over this 128-k tile
#pragma unroll
        for (int ks2 = 0; ks2 < 4; ++ks2) {
            bf16x8 wf = *(const bf16x8*)&wlds[(l15 * 128 + ks2 * 32 + l4 * 8) ^ swz];
#pragma unroll
            for (int df = 0; df < 4; ++df) {
                const u16* vb = vbase + (long)(df * 16) * 1024 + kt * 128 + ks2 * 32;
                bf16x8 vf = *(const bf16x8*)vb;
                o[df] = __builtin_amdgcn_mfma_f32_16x16x32_bf16(wf, vf, o[df], 0, 0, 0);
            }
        }
    }

    // finalize wave partial: full-row l (per q=l15)
    lsum += __shfl_xor(lsum, 16, 64);
    lsum += __shfl_xor(lsum, 32, 64);
    if (lane < 16) { cml[wave][0][l15] = m; cml[wave][1][l15] = lsum; }
#pragma unroll
    for (int df = 0; df < 4; ++df)
#pragma unroll
        for (int r = 0; r < 4; ++r)
            co[wave][l4 * 4 + r][df * 16 + l15] = o[df][r];
    __syncthreads();

    // combine 4 k-split partials; thread handles (q = tid>>4, d0 = (tid&15)*4)
    int q = tid >> 4, d0 = (tid & 15) * 4;
    float m0 = cml[0][0][q], m1 = cml[1][0][q], m2 = cml[2][0][q], m3 = cml[3][0][q];
    float ms = fmaxf(fmaxf(m0, m1), fmaxf(m2, m3));
    float c0w = __expf((m0 - ms) * SCALEF), c1w = __expf((m1 - ms) * SCALEF);
    float c2w = __expf((m2 - ms) * SCALEF), c3w = __expf((m3 - ms) * SCALEF);
    float lt = c0w * cml[0][1][q] + c1w * cml[1][1][q]
             + c2w * cml[2][1][q] + c3w * cml[3][1][q];
    f32x4 o0 = *(const f32x4*)&co[0][q][d0];
    f32x4 o1 = *(const f32x4*)&co[1][q][d0];
    f32x4 o2 = *(const f32x4*)&co[2][q][d0];
    f32x4 o3 = *(const f32x4*)&co[3][q][d0];
    float inv = __builtin_amdgcn_rcpf(lt);
    u16x4 st;
#pragma unroll
    for (int j = 0; j < 4; ++j)
        st[j] = f2bf((c0w * o0[j] + c1w * o1[j] + c2w * o2[j] + c3w * o3[j]) * inv);
    *(u16x4*)&XO[(long)(b * 512 + qg + q) * 1024 + h * 64 + d0] = st;
}

// ---------------------------------------------------------------------------
extern "C" void kernel_launch(void* const* d_in, const int* in_sizes, int n_in,
                              void* d_out, int out_size, void* d_ws, size_t ws_size,
                              hipStream_t stream)
{
    const float* q   = (const float*)d_in[0];
    const float* key = (const float*)d_in[1];
    const float* val = (const float*)d_in[2];
    const float* W   = (const float*)d_in[3];
    const float* ipb = (const float*)d_in[4];
    const float* ow  = (const float*)d_in[5];
    const float* ob  = (const float*)d_in[6];
    float* out = (float*)d_out;
    char* w = (char*)d_ws;

    // Workspace layout (bytes). Total 132,382,720 B (same as passing r3-r5).
    __half* PSIG   = (__half*)(w);                 // 64 MiB  (64,512,1024) fp16 sigmoid(phi)
    __half* ALPHAC = (__half*)(w + 67108864);      // 32 MiB  (64,256,1024) fp16 linear alpha
    float*  STATE  = (float*)(w + 100663296);      // 256 KiB (64,1024) f32
    u16*    XQAQ   = (u16*)(w + 100925440);        // 8 MiB   (2048,2048) bf16
    u16*    XK     = (u16*)(w + 109314048);        // 8 MiB   (4096,1024) bf16
    u16*    VT     = (u16*)(w + 117702656);        // 8 MiB   (64,64,1024) bf16
    u16*    XO     = (u16*)(w + 126091264);        // 4 MiB   (2048,1024) bf16
    u16*    OWBF   = (u16*)(w + 130285568);        // 2 MiB   (1024,1024) bf16
    // Overlays inside PSIG region (dead before phi GEMM writes):
    u16* QBF = (u16*)(w);                          // 4 MiB
    u16* KBF = (u16*)(w + 4194304);                // 8 MiB
    u16* VBF = (u16*)(w + 12582912);               // 8 MiB
    u16* WBF = (u16*)(w + 20971520);               // 8 MiB

    dim3 blk(256);

    // 0) f32 -> bf16 copies
    cvt_f32_bf16_k<<<dim3(2048), blk, 0, stream>>>(q, QBF, 524288);
    cvt_f32_bf16_k<<<dim3(4096), blk, 0, stream>>>(key, KBF, 1048576);
    cvt_f32_bf16_k<<<dim3(4096), blk, 0, stream>>>(val, VBF, 1048576);
    cvt_f32_bf16_k<<<dim3(4096), blk, 0, stream>>>(W, WBF, 1048576);
    cvt_f32_bf16_k<<<dim3(1024), blk, 0, stream>>>(ow, OWBF, 262144);

    // 1) XQAQ = q @ W[0:2048]^T + ipb[0:2048]  (cols 0..1023 = xqa, 1024.. = xq)
    mfma_nt<128, 128, 0><<<dim3(16, 16, 1), blk, 0, stream>>>(
        QBF, WBF, XQAQ, ipb, 1024, 1024, 1024, 2048, 0, 0, 0, 0, 0, 0, 1);
    // 2) XK = key @ W[2048:3072]^T + ipb[2048:3072]
    mfma_nt<128, 128, 0><<<dim3(8, 32, 1), blk, 0, stream>>>(
        KBF, WBF + 2097152, XK, ipb + 2048, 1024, 1024, 1024, 1024, 0, 0, 0, 0, 0, 0, 1);
    // 3) VT = transpose(val @ W[3072:4096]^T + ipb[3072:4096])
    mfma_nt<128, 128, 4><<<dim3(8, 32, 1), blk, 0, stream>>>(
        VBF, WBF + 3145728, VT, ipb + 3072, 1024, 1024, 1024, 0, 0, 0, 0, 0, 0, 0, 1);
    // 4) PSIG[n][q][k] = sigmoid(CLAMP * tanh(xqa_q . xk_k)) -> fp16
    mfma_nt<128, 128, 1><<<dim3(8, 4, 64), blk, 0, stream>>>(
        XQAQ, XK, PSIG, nullptr, 64, 2048, 1024, 1024,
        512L * 2048, 64, 1024L * 1024, 64, 8388608L, 524288L, 16);

    // 5) two 256-q chunks: DP -> fused attention (scores+softmax+PV)
    for (int c = 0; c < 2; ++c) {
        mono_dp_k<<<dim3(64), dim3(64), 0, stream>>>(PSIG, ALPHAC, STATE, c * 256);
        fused_attn_k<<<dim3(64, 16, 1), blk, 0, stream>>>(
            XQAQ, XK, VT, ALPHAC, XO, c * 256);
    }

    // 6) out = XO @ ow^T + ob  (f32)
    mfma_nt<128, 128, 3><<<dim3(8, 16, 1), blk, 0, stream>>>(
        XO, OWBF, out, ob, 1024, 1024, 1024, 1024, 0, 0, 0, 0, 0, 0, 1);
}

// Round 7
// 324.485 us; speedup vs baseline: 1.3068x; 1.0639x over previous
//
#include <hip/hip_runtime.h>
#include <hip/hip_fp16.h>
#include <hip/hip_bf16.h>
#include <math.h>

typedef unsigned short u16;
typedef __attribute__((ext_vector_type(8))) short bf16x8;
typedef __attribute__((ext_vector_type(8))) unsigned short u16x8;
typedef __attribute__((ext_vector_type(4))) unsigned short u16x4;
typedef __attribute__((ext_vector_type(4))) float f32x4;

static constexpr float NEGF = -1e30f;
static constexpr float CLAMPF = 3.8918202981106265f; // -log(1/0.98 - 1)
static constexpr float SCALEF = 0.125f;              // 1/sqrt(64)
static constexpr float ASCALE = 16384.f;             // 2^14 alpha storage scale

__device__ __forceinline__ u16 f2bf(float x) {
    __hip_bfloat16 h = __float2bfloat16(x);
    return *reinterpret_cast<u16*>(&h);
}
__device__ __forceinline__ float bf2f(u16 b) {
    unsigned int u = ((unsigned int)b) << 16;
    return __uint_as_float(u);
}

// ---------------------------------------------------------------------------
// f32 -> bf16 conversion (vectorized 4/thread)
// ---------------------------------------------------------------------------
__global__ __launch_bounds__(256)
void cvt_f32_bf16_k(const float* __restrict__ src, u16* __restrict__ dst, int n4)
{
    int i = blockIdx.x * 256 + threadIdx.x;
    if (i < n4) {
        float4 v = ((const float4*)src)[i];
        u16x4 o; o.x = f2bf(v.x); o.y = f2bf(v.y); o.z = f2bf(v.z); o.w = f2bf(v.w);
        ((u16x4*)dst)[i] = o;
    }
}

// ---------------------------------------------------------------------------
// bf16 MFMA GEMM, NT form: C[m][n] = sum_k A[m][k]*B[n][k]  (+ epilogue)
// Tile TM x TN, BK=64, 256 threads = 4 waves in 2x2 grid, mfma_f32_16x16x32_bf16.
// EPI: 0=bf16(+opt bias), 1=fp16 sigmoid(CLAMP*tanh(x)) (fast rcp), 3=f32+bias,
//      4=bf16 V-transpose store (VT[(b*16+h)*64+d][k]) + bias
// ---------------------------------------------------------------------------
template<int TM, int TN, int EPI>
__global__ __launch_bounds__(256)
void mfma_nt(const u16* __restrict__ Ag, const u16* __restrict__ Bg,
             void* __restrict__ Cg, const float* __restrict__ bias,
             int K, int lda, int ldb, int ldc,
             long sAb, long sAh, long sBb, long sBh, long sCb, long sCh,
             int hdiv)
{
    __shared__ u16 As[TM * 64];
    __shared__ u16 Bs[TN * 64];

    int z = blockIdx.z;
    int b = z / hdiv, h = z % hdiv;
    const u16* A = Ag + (long)b * sAb + (long)h * sAh;
    const u16* B = Bg + (long)b * sBb + (long)h * sBh;

    int tid = threadIdx.x;
    int bm = blockIdx.y * TM, bn = blockIdx.x * TN;

    constexpr int AC = TM / 32;
    constexpr int BC = TN / 32;
    int srow = tid >> 3;          // 0..31
    int scol = (tid & 7) * 8;     // 0..56

    int wid = tid >> 6, lane = tid & 63;
    int wr = wid >> 1, wc = wid & 1;
    constexpr int MI = TM / 32;
    constexpr int NI = TN / 32;
    int arow0 = wr * (TM / 2) + (lane & 15);
    int bcol0 = wc * (TN / 2) + (lane & 15);
    int koff = (lane >> 4) * 8;

    f32x4 acc[MI][NI];
#pragma unroll
    for (int i = 0; i < MI; ++i)
#pragma unroll
        for (int j = 0; j < NI; ++j) acc[i][j] = (f32x4){0.f, 0.f, 0.f, 0.f};

    for (int kt = 0; kt < K; kt += 64) {
        u16x8 av[AC], bv[BC];
#pragma unroll
        for (int c = 0; c < AC; ++c)
            av[c] = *(const u16x8*)(A + (long)(bm + srow + 32 * c) * lda + kt + scol);
#pragma unroll
        for (int c = 0; c < BC; ++c)
            bv[c] = *(const u16x8*)(B + (long)(bn + srow + 32 * c) * ldb + kt + scol);
        __syncthreads();
#pragma unroll
        for (int c = 0; c < AC; ++c)
            *(u16x8*)&As[(srow + 32 * c) * 64 + scol] = av[c];
#pragma unroll
        for (int c = 0; c < BC; ++c)
            *(u16x8*)&Bs[(srow + 32 * c) * 64 + scol] = bv[c];
        __syncthreads();

#pragma unroll
        for (int ks = 0; ks < 2; ++ks) {
            bf16x8 af[MI], bfr[NI];
#pragma unroll
            for (int mi = 0; mi < MI; ++mi)
                af[mi] = *(const bf16x8*)&As[(arow0 + 16 * mi) * 64 + ks * 32 + koff];
#pragma unroll
            for (int ni = 0; ni < NI; ++ni)
                bfr[ni] = *(const bf16x8*)&Bs[(bcol0 + 16 * ni) * 64 + ks * 32 + koff];
#pragma unroll
            for (int mi = 0; mi < MI; ++mi)
#pragma unroll
                for (int ni = 0; ni < NI; ++ni)
                    acc[mi][ni] = __builtin_amdgcn_mfma_f32_16x16x32_bf16(
                        af[mi], bfr[ni], acc[mi][ni], 0, 0, 0);
        }
    }

    // Epilogue
    int rbase = bm + wr * (TM / 2) + (lane >> 4) * 4;
    int cbase = bn + wc * (TN / 2) + (lane & 15);
#pragma unroll
    for (int mi = 0; mi < MI; ++mi) {
#pragma unroll
        for (int ni = 0; ni < NI; ++ni) {
            int m0 = rbase + 16 * mi;
            int n = cbase + 16 * ni;
            if constexpr (EPI == 0) {
                u16* C = (u16*)Cg + (long)b * sCb + (long)h * sCh;
                float bvv = bias ? bias[n] : 0.f;
#pragma unroll
                for (int r = 0; r < 4; ++r)
                    C[(long)(m0 + r) * ldc + n] = f2bf(acc[mi][ni][r] + bvv);
            } else if constexpr (EPI == 1) {
                __half* C = (__half*)Cg + (long)b * sCb + (long)h * sCh;
#pragma unroll
                for (int r = 0; r < 4; ++r) {
                    float x = acc[mi][ni][r];
                    float e2 = __expf(2.f * x);
                    float tv = CLAMPF - (2.f * CLAMPF) * __builtin_amdgcn_rcpf(e2 + 1.f);
                    float pv = __builtin_amdgcn_rcpf(1.f + __expf(-tv));
                    C[(long)(m0 + r) * ldc + n] = __float2half(pv);
                }
            } else if constexpr (EPI == 3) {
                float* C = (float*)Cg + (long)b * sCb + (long)h * sCh;
                float bvv = bias[n];
#pragma unroll
                for (int r = 0; r < 4; ++r)
                    C[(long)(m0 + r) * ldc + n] = acc[mi][ni][r] + bvv;
            } else { // EPI == 4: VT[(b16h)*64 + d][k] = V[m=b*1024+k][n=h*64+d]
                u16* C = (u16*)Cg;
                float bvv = bias[n];
                long vaddr = ((long)((m0 >> 10) * 16 + (n >> 6)) * 64 + (n & 63)) * 1024
                             + (m0 & 1023);
                u16x4 pk;
                pk.x = f2bf(acc[mi][ni][0] + bvv);
                pk.y = f2bf(acc[mi][ni][1] + bvv);
                pk.z = f2bf(acc[mi][ni][2] + bvv);
                pk.w = f2bf(acc[mi][ni][3] + bvv);
                *(u16x4*)(C + vaddr) = pk;
            }
        }
    }
}

// ---------------------------------------------------------------------------
// Monotonic DP, LINEAR probability domain (scaled by 2^14; mass-conserving so
// no rescaling needed). One WAVE per (b,h) slice; lane owns 16 contiguous k.
// a_new[i] = a[i]*p[i] + a[i-1]*(1-p[i-1]); shift via shfl_up. No LDS/barrier.
// Chunked over q (alpha cols [q0, q0+256)); f32 state carried in STATE.
// Depth-8 prefetch with statically named registers (latency ~600-900cy / 8).
// ---------------------------------------------------------------------------
struct pv16 { uint4 lo, hi; };

__device__ __forceinline__ pv16 dp_load(const __half* p, int col, int i0) {
    pv16 r;
    const uint4* src = (const uint4*)(p + (long)col * 1024 + i0);
    r.lo = src[0]; r.hi = src[1];
    return r;
}

#define DP_STEP(PC, J) do { \
    const __half2* hp = (const __half2*)&(PC); \
    float t[16], u[16]; \
    _Pragma("unroll") \
    for (int r8 = 0; r8 < 8; ++r8) { \
        float2 f = __half22float2(hp[r8]); \
        t[2 * r8]     = a[2 * r8]     * f.x; \
        t[2 * r8 + 1] = a[2 * r8 + 1] * f.y; \
    } \
    _Pragma("unroll") \
    for (int r = 0; r < 16; ++r) u[r] = a[r] - t[r]; \
    float up = __shfl_up(u[15], 1, 64); \
    if (lane == 0) up = 0.f; \
    a[0] = t[0] + up; \
    _Pragma("unroll") \
    for (int r = 1; r < 16; ++r) a[r] = t[r] + u[r - 1]; \
    uint4 o0, o1; \
    { __half2 h0 = __floats2half2_rn(a[0], a[1]),  h1 = __floats2half2_rn(a[2], a[3]); \
      __half2 h2 = __floats2half2_rn(a[4], a[5]),  h3 = __floats2half2_rn(a[6], a[7]); \
      o0.x = *(unsigned*)&h0; o0.y = *(unsigned*)&h1; o0.z = *(unsigned*)&h2; o0.w = *(unsigned*)&h3; \
      __half2 h4 = __floats2half2_rn(a[8], a[9]),  h5 = __floats2half2_rn(a[10], a[11]); \
      __half2 h6 = __floats2half2_rn(a[12], a[13]), h7 = __floats2half2_rn(a[14], a[15]); \
      o1.x = *(unsigned*)&h4; o1.y = *(unsigned*)&h5; o1.z = *(unsigned*)&h6; o1.w = *(unsigned*)&h7; } \
    uint4* dst = (uint4*)(al + (long)((J) - q0) * 1024 + i0); \
    dst[0] = o0; dst[1] = o1; \
} while (0)

__global__ __launch_bounds__(64)
void mono_dp_k(const __half* __restrict__ P, __half* __restrict__ AL,
               float* __restrict__ STATE, int q0)
{
    int n = blockIdx.x;
    int lane = threadIdx.x;                 // 0..63
    const __half* p = P + (long)n * 524288; // (512,1024) sigmoid probs
    __half* al = AL + (long)n * 262144;     // (256,1024) alpha chunk (scaled lin)
    float* stt = STATE + (long)n * 1024;
    int i0 = lane * 16;

    float a[16];
    if (q0 == 0) {
#pragma unroll
        for (int r = 0; r < 16; ++r) a[r] = 0.f;
        if (lane == 0) a[0] = ASCALE;
        // alpha column 0 = init distribution
        uint4 o0, o1;
        __half2 h0 = __floats2half2_rn(a[0], a[1]), h1 = __floats2half2_rn(a[2], a[3]);
        __half2 h2 = __floats2half2_rn(a[4], a[5]), h3 = __floats2half2_rn(a[6], a[7]);
        o0.x = *(unsigned*)&h0; o0.y = *(unsigned*)&h1; o0.z = *(unsigned*)&h2; o0.w = *(unsigned*)&h3;
        __half2 h4 = __floats2half2_rn(a[8], a[9]), h5 = __floats2half2_rn(a[10], a[11]);
        __half2 h6 = __floats2half2_rn(a[12], a[13]), h7 = __floats2half2_rn(a[14], a[15]);
        o1.x = *(unsigned*)&h4; o1.y = *(unsigned*)&h5; o1.z = *(unsigned*)&h6; o1.w = *(unsigned*)&h7;
        uint4* dst = (uint4*)(al + i0);
        dst[0] = o0; dst[1] = o1;
    } else {
#pragma unroll
        for (int r4 = 0; r4 < 4; ++r4) {
            float4 s = *(const float4*)(stt + i0 + 4 * r4);
            a[4 * r4 + 0] = s.x; a[4 * r4 + 1] = s.y;
            a[4 * r4 + 2] = s.z; a[4 * r4 + 3] = s.w;
        }
    }

    int jbeg = (q0 == 0) ? 1 : q0;
    int jend = q0 + 256;

    // depth-8 prefetch with statically named registers
    int j = jbeg;
    pv16 f0 = dp_load(p, j - 1, i0);
    pv16 f1 = dp_load(p, min(j + 0, 511), i0);
    pv16 f2 = dp_load(p, min(j + 1, 511), i0);
    pv16 f3 = dp_load(p, min(j + 2, 511), i0);
    pv16 f4 = dp_load(p, min(j + 3, 511), i0);
    pv16 f5 = dp_load(p, min(j + 4, 511), i0);
    pv16 f6 = dp_load(p, min(j + 5, 511), i0);
    pv16 f7 = dp_load(p, min(j + 6, 511), i0);

    while (j + 7 < jend) {
        DP_STEP(f0, j); f0 = dp_load(p, min(j + 7, 511), i0); ++j;
        DP_STEP(f1, j); f1 = dp_load(p, min(j + 7, 511), i0); ++j;
        DP_STEP(f2, j); f2 = dp_load(p, min(j + 7, 511), i0); ++j;
        DP_STEP(f3, j); f3 = dp_load(p, min(j + 7, 511), i0); ++j;
        DP_STEP(f4, j); f4 = dp_load(p, min(j + 7, 511), i0); ++j;
        DP_STEP(f5, j); f5 = dp_load(p, min(j + 7, 511), i0); ++j;
        DP_STEP(f6, j); f6 = dp_load(p, min(j + 7, 511), i0); ++j;
        DP_STEP(f7, j); f7 = dp_load(p, min(j + 7, 511), i0); ++j;
    }
    while (j < jend) {
        DP_STEP(f0, j);
        f0 = f1; f1 = f2; f2 = f3; f3 = f4; f4 = f5; f5 = f6; f6 = f7;
        ++j;
    }

#pragma unroll
    for (int r4 = 0; r4 < 4; ++r4) {
        float4 s;
        s.x = a[4 * r4 + 0]; s.y = a[4 * r4 + 1];
        s.z = a[4 * r4 + 2]; s.w = a[4 * r4 + 3];
        *(float4*)(stt + i0 + 4 * r4) = s;
    }
}

// ---------------------------------------------------------------------------
// Fused attention, single-pass online softmax with 4-way k-split.
// grid (64 n, 16 q-groups); block = 4 waves; wave w handles 16 q x 256 k
// (k in [w*256,(w+1)*256)). Per 128-k tile: scores via MFMA (swapped: lane's
// l15 = q), tile-max, online rescale, w = alpha*exp(SCALE*(s-m)) -> swizzled
// wave-private LDS -> PV MFMA. Partials (m,l,o) combined across waves in LDS.
// ---------------------------------------------------------------------------
__global__ __launch_bounds__(256, 4)
void fused_attn_k(const u16* __restrict__ XQAQ, const u16* __restrict__ XK,
                  const u16* __restrict__ VT, const __half* __restrict__ AL,
                  u16* __restrict__ XO, int c0)
{
    __shared__ u16 wtile[4][2048];     // per-wave 16q x 128k bf16 (swizzled)
    __shared__ float co[4][16][64];    // per-wave partial O (q, d)
    __shared__ float cml[4][2][16];    // per-wave m, l per q

    int n = blockIdx.x; int b = n >> 4, h = n & 15;
    int tid = threadIdx.x, wave = tid >> 6, lane = tid & 63;
    int l15 = lane & 15, l4 = lane >> 4;
    int qc = blockIdx.y * 16;          // q base within chunk [0,256)
    int qg = c0 + qc;                  // q base within 512
    u16* wlds = wtile[wave];
    int swz = (l15 & 7) << 3;

    // Q B-frags (col=q=l15), hoisted
    const u16* qbase = XQAQ + (long)(b * 512 + qg + l15) * 2048 + 1024 + h * 64 + l4 * 8;
    bf16x8 qf0 = *(const bf16x8*)(qbase);
    bf16x8 qf1 = *(const bf16x8*)(qbase + 32);

    const u16* kbase = XK + (long)(b * 1024 + wave * 256 + l15) * 1024 + h * 64 + l4 * 8;
    const __half* abase = AL + (long)(n * 256 + qc + l15) * 1024 + wave * 256 + l4 * 4;
    const u16* vbase = VT + (long)(n * 64 + l15) * 1024 + wave * 256 + l4 * 8;

    float m = -3.0e38f, lsum = 0.f;
    f32x4 o[4];
#pragma unroll
    for (int df = 0; df < 4; ++df) o[df] = (f32x4){0.f, 0.f, 0.f, 0.f};

    for (int kt = 0; kt < 2; ++kt) {
        // alpha regs for this tile (q=l15, k = kt*128 + kf*16 + l4*4 + r)
        uint2 areg[8];
#pragma unroll
        for (int kf = 0; kf < 8; ++kf)
            areg[kf] = *(const uint2*)(abase + kt * 128 + kf * 16);

        // scores: s[kf][r] for q=l15, k = kt*128 + kf*16 + l4*4 + r
        f32x4 s[8];
#pragma unroll
        for (int kf = 0; kf < 8; ++kf) {
            const u16* kb = kbase + (long)(kt * 128 + kf * 16) * 1024;
            bf16x8 k0 = *(const bf16x8*)kb;
            bf16x8 k1 = *(const bf16x8*)(kb + 32);
            f32x4 acc = (f32x4){0.f, 0.f, 0.f, 0.f};
            acc = __builtin_amdgcn_mfma_f32_16x16x32_bf16(k0, qf0, acc, 0, 0, 0);
            acc = __builtin_amdgcn_mfma_f32_16x16x32_bf16(k1, qf1, acc, 0, 0, 0);
            s[kf] = acc;
        }

        // tile max per q (in-lane over 32 vals, then across l4 groups)
        float mt = -3.0e38f;
#pragma unroll
        for (int kf = 0; kf < 8; ++kf)
            mt = fmaxf(mt, fmaxf(fmaxf(s[kf][0], s[kf][1]), fmaxf(s[kf][2], s[kf][3])));
        mt = fmaxf(mt, __shfl_xor(mt, 16, 64));
        mt = fmaxf(mt, __shfl_xor(mt, 32, 64));

        float mn = fmaxf(m, mt);
        float f = __expf((m - mn) * SCALEF);
        m = mn;
        float negm = -mn * SCALEF;
        lsum *= f;
        // rescale o rows (q = l4*4 + r needs f from lane l4*4+r)
        float fr0 = __shfl(f, l4 * 4 + 0, 64);
        float fr1 = __shfl(f, l4 * 4 + 1, 64);
        float fr2 = __shfl(f, l4 * 4 + 2, 64);
        float fr3 = __shfl(f, l4 * 4 + 3, 64);
#pragma unroll
        for (int df = 0; df < 4; ++df) {
            o[df][0] *= fr0; o[df][1] *= fr1; o[df][2] *= fr2; o[df][3] *= fr3;
        }

        // w = alpha * exp(SCALE*(s - m)), accumulate l, store swizzled LDS
#pragma unroll
        for (int kf = 0; kf < 8; ++kf) {
            float2 a01 = __half22float2(*(__half2*)&areg[kf].x);
            float2 a23 = __half22float2(*(__half2*)&areg[kf].y);
            float w0 = a01.x * __expf(fmaf(s[kf][0], SCALEF, negm));
            float w1 = a01.y * __expf(fmaf(s[kf][1], SCALEF, negm));
            float w2 = a23.x * __expf(fmaf(s[kf][2], SCALEF, negm));
            float w3 = a23.y * __expf(fmaf(s[kf][3], SCALEF, negm));
            lsum += (w0 + w1) + (w2 + w3);
            u16x4 wp; wp.x = f2bf(w0); wp.y = f2bf(w1); wp.z = f2bf(w2); wp.w = f2bf(w3);
            *(u16x4*)&wlds[(l15 * 128 + kf * 16 + l4 * 4) ^ swz] = wp;
        }

        // PV over this 128-k tile
#pragma unroll
        for (int ks2 = 0; ks2 < 4; ++ks2) {
            bf16x8 wf = *(const bf16x8*)&wlds[(l15 * 128 + ks2 * 32 + l4 * 8) ^ swz];
#pragma unroll
            for (int df = 0; df < 4; ++df) {
                const u16* vb = vbase + (long)(df * 16) * 1024 + kt * 128 + ks2 * 32;
                bf16x8 vf = *(const bf16x8*)vb;
                o[df] = __builtin_amdgcn_mfma_f32_16x16x32_bf16(wf, vf, o[df], 0, 0, 0);
            }
        }
    }

    // finalize wave partial: full-row l (per q=l15)
    lsum += __shfl_xor(lsum, 16, 64);
    lsum += __shfl_xor(lsum, 32, 64);
    if (lane < 16) { cml[wave][0][l15] = m; cml[wave][1][l15] = lsum; }
#pragma unroll
    for (int df = 0; df < 4; ++df)
#pragma unroll
        for (int r = 0; r < 4; ++r)
            co[wave][l4 * 4 + r][df * 16 + l15] = o[df][r];
    __syncthreads();

    // combine 4 k-split partials; thread handles (q = tid>>4, d0 = (tid&15)*4)
    int q = tid >> 4, d0 = (tid & 15) * 4;
    float m0 = cml[0][0][q], m1 = cml[1][0][q], m2 = cml[2][0][q], m3 = cml[3][0][q];
    float ms = fmaxf(fmaxf(m0, m1), fmaxf(m2, m3));
    float c0w = __expf((m0 - ms) * SCALEF), c1w = __expf((m1 - ms) * SCALEF);
    float c2w = __expf((m2 - ms) * SCALEF), c3w = __expf((m3 - ms) * SCALEF);
    float lt = c0w * cml[0][1][q] + c1w * cml[1][1][q]
             + c2w * cml[2][1][q] + c3w * cml[3][1][q];
    f32x4 o0 = *(const f32x4*)&co[0][q][d0];
    f32x4 o1 = *(const f32x4*)&co[1][q][d0];
    f32x4 o2 = *(const f32x4*)&co[2][q][d0];
    f32x4 o3 = *(const f32x4*)&co[3][q][d0];
    float inv = __builtin_amdgcn_rcpf(lt);
    u16x4 st;
#pragma unroll
    for (int j = 0; j < 4; ++j)
        st[j] = f2bf((c0w * o0[j] + c1w * o1[j] + c2w * o2[j] + c3w * o3[j]) * inv);
    *(u16x4*)&XO[(long)(b * 512 + qg + q) * 1024 + h * 64 + d0] = st;
}

// ---------------------------------------------------------------------------
extern "C" void kernel_launch(void* const* d_in, const int* in_sizes, int n_in,
                              void* d_out, int out_size, void* d_ws, size_t ws_size,
                              hipStream_t stream)
{
    const float* q   = (const float*)d_in[0];
    const float* key = (const float*)d_in[1];
    const float* val = (const float*)d_in[2];
    const float* W   = (const float*)d_in[3];
    const float* ipb = (const float*)d_in[4];
    const float* ow  = (const float*)d_in[5];
    const float* ob  = (const float*)d_in[6];
    float* out = (float*)d_out;
    char* w = (char*)d_ws;

    // Workspace layout (bytes). Total 132,382,720 B (same as passing r3-r6).
    __half* PSIG   = (__half*)(w);                 // 64 MiB  (64,512,1024) fp16 sigmoid(phi)
    __half* ALPHAC = (__half*)(w + 67108864);      // 32 MiB  (64,256,1024) fp16 linear alpha
    float*  STATE  = (float*)(w + 100663296);      // 256 KiB (64,1024) f32
    u16*    XQAQ   = (u16*)(w + 100925440);        // 8 MiB   (2048,2048) bf16
    u16*    XK     = (u16*)(w + 109314048);        // 8 MiB   (4096,1024) bf16
    u16*    VT     = (u16*)(w + 117702656);        // 8 MiB   (64,64,1024) bf16
    u16*    XO     = (u16*)(w + 126091264);        // 4 MiB   (2048,1024) bf16
    u16*    OWBF   = (u16*)(w + 130285568);        // 2 MiB   (1024,1024) bf16
    // Overlays inside PSIG region (dead before phi GEMM writes):
    u16* QBF = (u16*)(w);                          // 4 MiB
    u16* KBF = (u16*)(w + 4194304);                // 8 MiB
    u16* VBF = (u16*)(w + 12582912);               // 8 MiB
    u16* WBF = (u16*)(w + 20971520);               // 8 MiB

    dim3 blk(256);

    // 0) f32 -> bf16 copies
    cvt_f32_bf16_k<<<dim3(2048), blk, 0, stream>>>(q, QBF, 524288);
    cvt_f32_bf16_k<<<dim3(4096), blk, 0, stream>>>(key, KBF, 1048576);
    cvt_f32_bf16_k<<<dim3(4096), blk, 0, stream>>>(val, VBF, 1048576);
    cvt_f32_bf16_k<<<dim3(4096), blk, 0, stream>>>(W, WBF, 1048576);
    cvt_f32_bf16_k<<<dim3(1024), blk, 0, stream>>>(ow, OWBF, 262144);

    // 1) XQAQ = q @ W[0:2048]^T + ipb[0:2048]  (cols 0..1023 = xqa, 1024.. = xq)
    mfma_nt<128, 128, 0><<<dim3(16, 16, 1), blk, 0, stream>>>(
        QBF, WBF, XQAQ, ipb, 1024, 1024, 1024, 2048, 0, 0, 0, 0, 0, 0, 1);
    // 2) XK = key @ W[2048:3072]^T + ipb[2048:3072]
    mfma_nt<128, 128, 0><<<dim3(8, 32, 1), blk, 0, stream>>>(
        KBF, WBF + 2097152, XK, ipb + 2048, 1024, 1024, 1024, 1024, 0, 0, 0, 0, 0, 0, 1);
    // 3) VT = transpose(val @ W[3072:4096]^T + ipb[3072:4096])
    mfma_nt<128, 128, 4><<<dim3(8, 32, 1), blk, 0, stream>>>(
        VBF, WBF + 3145728, VT, ipb + 3072, 1024, 1024, 1024, 0, 0, 0, 0, 0, 0, 0, 1);
    // 4) PSIG[n][q][k] = sigmoid(CLAMP * tanh(xqa_q . xk_k)) -> fp16
    mfma_nt<128, 128, 1><<<dim3(8, 4, 64), blk, 0, stream>>>(
        XQAQ, XK, PSIG, nullptr, 64, 2048, 1024, 1024,
        512L * 2048, 64, 1024L * 1024, 64, 8388608L, 524288L, 16);

    // 5) two 256-q chunks: DP -> fused attention (scores+softmax+PV)
    for (int c = 0; c < 2; ++c) {
        mono_dp_k<<<dim3(64), dim3(64), 0, stream>>>(PSIG, ALPHAC, STATE, c * 256);
        fused_attn_k<<<dim3(64, 16, 1), blk, 0, stream>>>(
            XQAQ, XK, VT, ALPHAC, XO, c * 256);
    }

    // 6) out = XO @ ow^T + ob  (f32)
    mfma_nt<128, 128, 3><<<dim3(8, 16, 1), blk, 0, stream>>>(
        XO, OWBF, out, ob, 1024, 1024, 1024, 1024, 0, 0, 0, 0, 0, 0, 1);
}

// Round 8
// 313.935 us; speedup vs baseline: 1.3507x; 1.0336x over previous
//
#include <hip/hip_runtime.h>
#include <hip/hip_fp16.h>
#include <hip/hip_bf16.h>
#include <math.h>

typedef unsigned short u16;
typedef __attribute__((ext_vector_type(8))) short bf16x8;
typedef __attribute__((ext_vector_type(8))) unsigned short u16x8;
typedef __attribute__((ext_vector_type(4))) unsigned short u16x4;
typedef __attribute__((ext_vector_type(4))) float f32x4;

static constexpr float NEGF = -1e30f;
static constexpr float CLAMPF = 3.8918202981106265f; // -log(1/0.98 - 1)
static constexpr float SCALEF = 0.125f;              // 1/sqrt(64)
static constexpr float ASCALE = 16384.f;             // 2^14 alpha storage scale

__device__ __forceinline__ u16 f2bf(float x) {
    __hip_bfloat16 h = __float2bfloat16(x);
    return *reinterpret_cast<u16*>(&h);
}
__device__ __forceinline__ float bf2f(u16 b) {
    unsigned int u = ((unsigned int)b) << 16;
    return __uint_as_float(u);
}

// ---------------------------------------------------------------------------
// f32 -> bf16 conversion (vectorized 4/thread)
// ---------------------------------------------------------------------------
__global__ __launch_bounds__(256)
void cvt_f32_bf16_k(const float* __restrict__ src, u16* __restrict__ dst, int n4)
{
    int i = blockIdx.x * 256 + threadIdx.x;
    if (i < n4) {
        float4 v = ((const float4*)src)[i];
        u16x4 o; o.x = f2bf(v.x); o.y = f2bf(v.y); o.z = f2bf(v.z); o.w = f2bf(v.w);
        ((u16x4*)dst)[i] = o;
    }
}

// ---------------------------------------------------------------------------
// bf16 MFMA GEMM, NT form: C[m][n] = sum_k A[m][k]*B[n][k]  (+ epilogue)
// Tile TM x TN, BK=64, 256 threads = 4 waves in 2x2 grid, mfma_f32_16x16x32_bf16.
// EPI: 0=bf16(+opt bias), 1=fp16 sigmoid(CLAMP*tanh(x)) (fast rcp), 3=f32+bias,
//      4=bf16 V-transpose store (VT[(b*16+h)*64+d][k]) + bias
// ---------------------------------------------------------------------------
template<int TM, int TN, int EPI>
__global__ __launch_bounds__(256)
void mfma_nt(const u16* __restrict__ Ag, const u16* __restrict__ Bg,
             void* __restrict__ Cg, const float* __restrict__ bias,
             int K, int lda, int ldb, int ldc,
             long sAb, long sAh, long sBb, long sBh, long sCb, long sCh,
             int hdiv)
{
    __shared__ u16 As[TM * 64];
    __shared__ u16 Bs[TN * 64];

    int z = blockIdx.z;
    int b = z / hdiv, h = z % hdiv;
    const u16* A = Ag + (long)b * sAb + (long)h * sAh;
    const u16* B = Bg + (long)b * sBb + (long)h * sBh;

    int tid = threadIdx.x;
    int bm = blockIdx.y * TM, bn = blockIdx.x * TN;

    constexpr int AC = TM / 32;
    constexpr int BC = TN / 32;
    int srow = tid >> 3;          // 0..31
    int scol = (tid & 7) * 8;     // 0..56

    int wid = tid >> 6, lane = tid & 63;
    int wr = wid >> 1, wc = wid & 1;
    constexpr int MI = TM / 32;
    constexpr int NI = TN / 32;
    int arow0 = wr * (TM / 2) + (lane & 15);
    int bcol0 = wc * (TN / 2) + (lane & 15);
    int koff = (lane >> 4) * 8;

    f32x4 acc[MI][NI];
#pragma unroll
    for (int i = 0; i < MI; ++i)
#pragma unroll
        for (int j = 0; j < NI; ++j) acc[i][j] = (f32x4){0.f, 0.f, 0.f, 0.f};

    for (int kt = 0; kt < K; kt += 64) {
        u16x8 av[AC], bv[BC];
#pragma unroll
        for (int c = 0; c < AC; ++c)
            av[c] = *(const u16x8*)(A + (long)(bm + srow + 32 * c) * lda + kt + scol);
#pragma unroll
        for (int c = 0; c < BC; ++c)
            bv[c] = *(const u16x8*)(B + (long)(bn + srow + 32 * c) * ldb + kt + scol);
        __syncthreads();
#pragma unroll
        for (int c = 0; c < AC; ++c)
            *(u16x8*)&As[(srow + 32 * c) * 64 + scol] = av[c];
#pragma unroll
        for (int c = 0; c < BC; ++c)
            *(u16x8*)&Bs[(srow + 32 * c) * 64 + scol] = bv[c];
        __syncthreads();

#pragma unroll
        for (int ks = 0; ks < 2; ++ks) {
            bf16x8 af[MI], bfr[NI];
#pragma unroll
            for (int mi = 0; mi < MI; ++mi)
                af[mi] = *(const bf16x8*)&As[(arow0 + 16 * mi) * 64 + ks * 32 + koff];
#pragma unroll
            for (int ni = 0; ni < NI; ++ni)
                bfr[ni] = *(const bf16x8*)&Bs[(bcol0 + 16 * ni) * 64 + ks * 32 + koff];
#pragma unroll
            for (int mi = 0; mi < MI; ++mi)
#pragma unroll
                for (int ni = 0; ni < NI; ++ni)
                    acc[mi][ni] = __builtin_amdgcn_mfma_f32_16x16x32_bf16(
                        af[mi], bfr[ni], acc[mi][ni], 0, 0, 0);
        }
    }

    // Epilogue
    int rbase = bm + wr * (TM / 2) + (lane >> 4) * 4;
    int cbase = bn + wc * (TN / 2) + (lane & 15);
#pragma unroll
    for (int mi = 0; mi < MI; ++mi) {
#pragma unroll
        for (int ni = 0; ni < NI; ++ni) {
            int m0 = rbase + 16 * mi;
            int n = cbase + 16 * ni;
            if constexpr (EPI == 0) {
                u16* C = (u16*)Cg + (long)b * sCb + (long)h * sCh;
                float bvv = bias ? bias[n] : 0.f;
#pragma unroll
                for (int r = 0; r < 4; ++r)
                    C[(long)(m0 + r) * ldc + n] = f2bf(acc[mi][ni][r] + bvv);
            } else if constexpr (EPI == 1) {
                __half* C = (__half*)Cg + (long)b * sCb + (long)h * sCh;
#pragma unroll
                for (int r = 0; r < 4; ++r) {
                    float x = acc[mi][ni][r];
                    float e2 = __expf(2.f * x);
                    float tv = CLAMPF - (2.f * CLAMPF) * __builtin_amdgcn_rcpf(e2 + 1.f);
                    float pv = __builtin_amdgcn_rcpf(1.f + __expf(-tv));
                    C[(long)(m0 + r) * ldc + n] = __float2half(pv);
                }
            } else if constexpr (EPI == 3) {
                float* C = (float*)Cg + (long)b * sCb + (long)h * sCh;
                float bvv = bias[n];
#pragma unroll
                for (int r = 0; r < 4; ++r)
                    C[(long)(m0 + r) * ldc + n] = acc[mi][ni][r] + bvv;
            } else { // EPI == 4: VT[(b16h)*64 + d][k] = V[m=b*1024+k][n=h*64+d]
                u16* C = (u16*)Cg;
                float bvv = bias[n];
                long vaddr = ((long)((m0 >> 10) * 16 + (n >> 6)) * 64 + (n & 63)) * 1024
                             + (m0 & 1023);
                u16x4 pk;
                pk.x = f2bf(acc[mi][ni][0] + bvv);
                pk.y = f2bf(acc[mi][ni][1] + bvv);
                pk.z = f2bf(acc[mi][ni][2] + bvv);
                pk.w = f2bf(acc[mi][ni][3] + bvv);
                *(u16x4*)(C + vaddr) = pk;
            }
        }
    }
}

// ---------------------------------------------------------------------------
// Monotonic DP, LINEAR probability domain (scaled 2^14, mass-conserving).
// 4-way k-split: 256 threads (4 waves) per (b,h) slice; lane owns 4 k.
// c[i] = a[i]*(1-p[i]) depends only on OLD column state -> no serial chain
// within a column; shift via shfl_up + LDS wave-boundary (parity dbuf) +
// raw s_barrier (lgkmcnt only, global prefetch stays in flight).
// a_new[i] = fmaf(a[i], p[i], c[i-1]).  Depth-8 named-register prefetch.
// ---------------------------------------------------------------------------
#define DPL(J) (*(const uint2*)(p + (long)min((J), 511) * 1024 + k0))

#define DP_STEP2(PC, J) do { \
    float2 p01 = __half22float2(*(__half2*)&(PC).x); \
    float2 p23 = __half22float2(*(__half2*)&(PC).y); \
    float c0 = fmaf(-a0, p01.x, a0); \
    float c1 = fmaf(-a1, p01.y, a1); \
    float c2 = fmaf(-a2, p23.x, a2); \
    float c3 = fmaf(-a3, p23.y, a3); \
    float cp = __shfl_up(c3, 1, 64); \
    if (lane == 63) bound[(J) & 1][wave] = c3; \
    asm volatile("s_waitcnt lgkmcnt(0)" ::: "memory"); \
    __builtin_amdgcn_s_barrier(); \
    __builtin_amdgcn_sched_barrier(0); \
    if (lane == 0) cp = (wave == 0) ? 0.f : bound[(J) & 1][wave - 1]; \
    a0 = fmaf(a0, p01.x, cp); \
    a1 = fmaf(a1, p01.y, c0); \
    a2 = fmaf(a2, p23.x, c1); \
    a3 = fmaf(a3, p23.y, c2); \
    __half2 h01 = __floats2half2_rn(a0, a1), h23 = __floats2half2_rn(a2, a3); \
    uint2 st; st.x = *(unsigned*)&h01; st.y = *(unsigned*)&h23; \
    *(uint2*)(al + (long)((J) - q0) * 1024 + k0) = st; \
} while (0)

__global__ __launch_bounds__(256)
void mono_dp_k(const __half* __restrict__ P, __half* __restrict__ AL,
               float* __restrict__ STATE, int q0)
{
    int n = blockIdx.x;
    int tid = threadIdx.x;
    int wave = tid >> 6, lane = tid & 63;
    const __half* p = P + (long)n * 524288; // (512,1024) sigmoid probs
    __half* al = AL + (long)n * 262144;     // (256,1024) alpha chunk (scaled lin)
    float* stt = STATE + (long)n * 1024;
    int k0 = tid * 4;
    __shared__ float bound[2][4];

    float a0, a1, a2, a3;
    if (q0 == 0) {
        a0 = (tid == 0) ? ASCALE : 0.f; a1 = 0.f; a2 = 0.f; a3 = 0.f;
        __half2 h01 = __floats2half2_rn(a0, a1), h23 = __floats2half2_rn(a2, a3);
        uint2 st; st.x = *(unsigned*)&h01; st.y = *(unsigned*)&h23;
        *(uint2*)(al + k0) = st;   // alpha column 0 = init distribution
    } else {
        float4 s = *(const float4*)(stt + k0);
        a0 = s.x; a1 = s.y; a2 = s.z; a3 = s.w;
    }

    int jbeg = (q0 == 0) ? 1 : q0;
    int jend = q0 + 256;

    // depth-8 prefetch with statically named registers (8B each)
    int j = jbeg;
    uint2 f0 = DPL(j - 1);
    uint2 f1 = DPL(j + 0);
    uint2 f2 = DPL(j + 1);
    uint2 f3 = DPL(j + 2);
    uint2 f4 = DPL(j + 3);
    uint2 f5 = DPL(j + 4);
    uint2 f6 = DPL(j + 5);
    uint2 f7 = DPL(j + 6);

    while (j + 7 < jend) {
        DP_STEP2(f0, j); f0 = DPL(j + 7); ++j;
        DP_STEP2(f1, j); f1 = DPL(j + 7); ++j;
        DP_STEP2(f2, j); f2 = DPL(j + 7); ++j;
        DP_STEP2(f3, j); f3 = DPL(j + 7); ++j;
        DP_STEP2(f4, j); f4 = DPL(j + 7); ++j;
        DP_STEP2(f5, j); f5 = DPL(j + 7); ++j;
        DP_STEP2(f6, j); f6 = DPL(j + 7); ++j;
        DP_STEP2(f7, j); f7 = DPL(j + 7); ++j;
    }
    while (j < jend) {
        DP_STEP2(f0, j);
        f0 = f1; f1 = f2; f2 = f3; f3 = f4; f4 = f5; f5 = f6; f6 = f7;
        ++j;
    }

    float4 s; s.x = a0; s.y = a1; s.z = a2; s.w = a3;
    *(float4*)(stt + k0) = s;
}

// ---------------------------------------------------------------------------
// Fused attention, single-pass online softmax with 4-way k-split.
// grid (64 n, 16 q-groups); block = 4 waves; wave w handles 16 q x 256 k
// (k in [w*256,(w+1)*256)). Per 128-k tile: scores via MFMA (swapped: lane's
// l15 = q), tile-max, online rescale, w = alpha*exp(SCALE*(s-m)) -> swizzled
// wave-private LDS -> PV MFMA. Partials (m,l,o) combined across waves in LDS.
// ---------------------------------------------------------------------------
__global__ __launch_bounds__(256, 4)
void fused_attn_k(const u16* __restrict__ XQAQ, const u16* __restrict__ XK,
                  const u16* __restrict__ VT, const __half* __restrict__ AL,
                  u16* __restrict__ XO, int c0)
{
    __shared__ u16 wtile[4][2048];     // per-wave 16q x 128k bf16 (swizzled)
    __shared__ float co[4][16][64];    // per-wave partial O (q, d)
    __shared__ float cml[4][2][16];    // per-wave m, l per q

    int n = blockIdx.x; int b = n >> 4, h = n & 15;
    int tid = threadIdx.x, wave = tid >> 6, lane = tid & 63;
    int l15 = lane & 15, l4 = lane >> 4;
    int qc = blockIdx.y * 16;          // q base within chunk [0,256)
    int qg = c0 + qc;                  // q base within 512
    u16* wlds = wtile[wave];
    int swz = (l15 & 7) << 3;

    // Q B-frags (col=q=l15), hoisted
    const u16* qbase = XQAQ + (long)(b * 512 + qg + l15) * 2048 + 1024 + h * 64 + l4 * 8;
    bf16x8 qf0 = *(const bf16x8*)(qbase);
    bf16x8 qf1 = *(const bf16x8*)(qbase + 32);

    const u16* kbase = XK + (long)(b * 1024 + wave * 256 + l15) * 1024 + h * 64 + l4 * 8;
    const __half* abase = AL + (long)(n * 256 + qc + l15) * 1024 + wave * 256 + l4 * 4;
    const u16* vbase = VT + (long)(n * 64 + l15) * 1024 + wave * 256 + l4 * 8;

    float m = -3.0e38f, lsum = 0.f;
    f32x4 o[4];
#pragma unroll
    for (int df = 0; df < 4; ++df) o[df] = (f32x4){0.f, 0.f, 0.f, 0.f};

    for (int kt = 0; kt < 2; ++kt) {
        // alpha regs for this tile (q=l15, k = kt*128 + kf*16 + l4*4 + r)
        uint2 areg[8];
#pragma unroll
        for (int kf = 0; kf < 8; ++kf)
            areg[kf] = *(const uint2*)(abase + kt * 128 + kf * 16);

        // scores: s[kf][r] for q=l15, k = kt*128 + kf*16 + l4*4 + r
        f32x4 s[8];
#pragma unroll
        for (int kf = 0; kf < 8; ++kf) {
            const u16* kb = kbase + (long)(kt * 128 + kf * 16) * 1024;
            bf16x8 k0 = *(const bf16x8*)kb;
            bf16x8 k1 = *(const bf16x8*)(kb + 32);
            f32x4 acc = (f32x4){0.f, 0.f, 0.f, 0.f};
            acc = __builtin_amdgcn_mfma_f32_16x16x32_bf16(k0, qf0, acc, 0, 0, 0);
            acc = __builtin_amdgcn_mfma_f32_16x16x32_bf16(k1, qf1, acc, 0, 0, 0);
            s[kf] = acc;
        }

        // tile max per q (in-lane over 32 vals, then across l4 groups)
        float mt = -3.0e38f;
#pragma unroll
        for (int kf = 0; kf < 8; ++kf)
            mt = fmaxf(mt, fmaxf(fmaxf(s[kf][0], s[kf][1]), fmaxf(s[kf][2], s[kf][3])));
        mt = fmaxf(mt, __shfl_xor(mt, 16, 64));
        mt = fmaxf(mt, __shfl_xor(mt, 32, 64));

        float mn = fmaxf(m, mt);
        float f = __expf((m - mn) * SCALEF);
        m = mn;
        float negm = -mn * SCALEF;
        lsum *= f;
        // rescale o rows (q = l4*4 + r needs f from lane l4*4+r)
        float fr0 = __shfl(f, l4 * 4 + 0, 64);
        float fr1 = __shfl(f, l4 * 4 + 1, 64);
        float fr2 = __shfl(f, l4 * 4 + 2, 64);
        float fr3 = __shfl(f, l4 * 4 + 3, 64);
#pragma unroll
        for (int df = 0; df < 4; ++df) {
            o[df][0] *= fr0; o[df][1] *= fr1; o[df][2] *= fr2; o[df][3] *= fr3;
        }

        // w = alpha * exp(SCALE*(s - m)), accumulate l, store swizzled LDS
#pragma unroll
        for (int kf = 0; kf < 8; ++kf) {
            float2 a01 = __half22float2(*(__half2*)&areg[kf].x);
            float2 a23 = __half22float2(*(__half2*)&areg[kf].y);
            float w0 = a01.x * __expf(fmaf(s[kf][0], SCALEF, negm));
            float w1 = a01.y * __expf(fmaf(s[kf][1], SCALEF, negm));
            float w2 = a23.x * __expf(fmaf(s[kf][2], SCALEF, negm));
            float w3 = a23.y * __expf(fmaf(s[kf][3], SCALEF, negm));
            lsum += (w0 + w1) + (w2 + w3);
            u16x4 wp; wp.x = f2bf(w0); wp.y = f2bf(w1); wp.z = f2bf(w2); wp.w = f2bf(w3);
            *(u16x4*)&wlds[(l15 * 128 + kf * 16 + l4 * 4) ^ swz] = wp;
        }

        // PV over this 128-k tile
#pragma unroll
        for (int ks2 = 0; ks2 < 4; ++ks2) {
            bf16x8 wf = *(const bf16x8*)&wlds[(l15 * 128 + ks2 * 32 + l4 * 8) ^ swz];
#pragma unroll
            for (int df = 0; df < 4; ++df) {
                const u16* vb = vbase + (long)(df * 16) * 1024 + kt * 128 + ks2 * 32;
                bf16x8 vf = *(const bf16x8*)vb;
                o[df] = __builtin_amdgcn_mfma_f32_16x16x32_bf16(wf, vf, o[df], 0, 0, 0);
            }
        }
    }

    // finalize wave partial: full-row l (per q=l15)
    lsum += __shfl_xor(lsum, 16, 64);
    lsum += __shfl_xor(lsum, 32, 64);
    if (lane < 16) { cml[wave][0][l15] = m; cml[wave][1][l15] = lsum; }
#pragma unroll
    for (int df = 0; df < 4; ++df)
#pragma unroll
        for (int r = 0; r < 4; ++r)
            co[wave][l4 * 4 + r][df * 16 + l15] = o[df][r];
    __syncthreads();

    // combine 4 k-split partials; thread handles (q = tid>>4, d0 = (tid&15)*4)
    int q = tid >> 4, d0 = (tid & 15) * 4;
    float m0 = cml[0][0][q], m1 = cml[1][0][q], m2 = cml[2][0][q], m3 = cml[3][0][q];
    float ms = fmaxf(fmaxf(m0, m1), fmaxf(m2, m3));
    float c0w = __expf((m0 - ms) * SCALEF), c1w = __expf((m1 - ms) * SCALEF);
    float c2w = __expf((m2 - ms) * SCALEF), c3w = __expf((m3 - ms) * SCALEF);
    float lt = c0w * cml[0][1][q] + c1w * cml[1][1][q]
             + c2w * cml[2][1][q] + c3w * cml[3][1][q];
    f32x4 o0 = *(const f32x4*)&co[0][q][d0];
    f32x4 o1 = *(const f32x4*)&co[1][q][d0];
    f32x4 o2 = *(const f32x4*)&co[2][q][d0];
    f32x4 o3 = *(const f32x4*)&co[3][q][d0];
    float inv = __builtin_amdgcn_rcpf(lt);
    u16x4 st;
#pragma unroll
    for (int j = 0; j < 4; ++j)
        st[j] = f2bf((c0w * o0[j] + c1w * o1[j] + c2w * o2[j] + c3w * o3[j]) * inv);
    *(u16x4*)&XO[(long)(b * 512 + qg + q) * 1024 + h * 64 + d0] = st;
}

// ---------------------------------------------------------------------------
extern "C" void kernel_launch(void* const* d_in, const int* in_sizes, int n_in,
                              void* d_out, int out_size, void* d_ws, size_t ws_size,
                              hipStream_t stream)
{
    const float* q   = (const float*)d_in[0];
    const float* key = (const float*)d_in[1];
    const float* val = (const float*)d_in[2];
    const float* W   = (const float*)d_in[3];
    const float* ipb = (const float*)d_in[4];
    const float* ow  = (const float*)d_in[5];
    const float* ob  = (const float*)d_in[6];
    float* out = (float*)d_out;
    char* w = (char*)d_ws;

    // Workspace layout (bytes). Total 132,382,720 B (same as passing r3-r7).
    __half* PSIG   = (__half*)(w);                 // 64 MiB  (64,512,1024) fp16 sigmoid(phi)
    __half* ALPHAC = (__half*)(w + 67108864);      // 32 MiB  (64,256,1024) fp16 linear alpha
    float*  STATE  = (float*)(w + 100663296);      // 256 KiB (64,1024) f32
    u16*    XQAQ   = (u16*)(w + 100925440);        // 8 MiB   (2048,2048) bf16
    u16*    XK     = (u16*)(w + 109314048);        // 8 MiB   (4096,1024) bf16
    u16*    VT     = (u16*)(w + 117702656);        // 8 MiB   (64,64,1024) bf16
    u16*    XO     = (u16*)(w + 126091264);        // 4 MiB   (2048,1024) bf16
    u16*    OWBF   = (u16*)(w + 130285568);        // 2 MiB   (1024,1024) bf16
    // Overlays inside PSIG region (dead before phi GEMM writes):
    u16* QBF = (u16*)(w);                          // 4 MiB
    u16* KBF = (u16*)(w + 4194304);                // 8 MiB
    u16* VBF = (u16*)(w + 12582912);               // 8 MiB
    u16* WBF = (u16*)(w + 20971520);               // 8 MiB

    dim3 blk(256);

    // 0) f32 -> bf16 copies
    cvt_f32_bf16_k<<<dim3(2048), blk, 0, stream>>>(q, QBF, 524288);
    cvt_f32_bf16_k<<<dim3(4096), blk, 0, stream>>>(key, KBF, 1048576);
    cvt_f32_bf16_k<<<dim3(4096), blk, 0, stream>>>(val, VBF, 1048576);
    cvt_f32_bf16_k<<<dim3(4096), blk, 0, stream>>>(W, WBF, 1048576);
    cvt_f32_bf16_k<<<dim3(1024), blk, 0, stream>>>(ow, OWBF, 262144);

    // 1) XQAQ = q @ W[0:2048]^T + ipb[0:2048]  (cols 0..1023 = xqa, 1024.. = xq)
    mfma_nt<128, 128, 0><<<dim3(16, 16, 1), blk, 0, stream>>>(
        QBF, WBF, XQAQ, ipb, 1024, 1024, 1024, 2048, 0, 0, 0, 0, 0, 0, 1);
    // 2) XK = key @ W[2048:3072]^T + ipb[2048:3072]
    mfma_nt<128, 128, 0><<<dim3(8, 32, 1), blk, 0, stream>>>(
        KBF, WBF + 2097152, XK, ipb + 2048, 1024, 1024, 1024, 1024, 0, 0, 0, 0, 0, 0, 1);
    // 3) VT = transpose(val @ W[3072:4096]^T + ipb[3072:4096])
    mfma_nt<128, 128, 4><<<dim3(8, 32, 1), blk, 0, stream>>>(
        VBF, WBF + 3145728, VT, ipb + 3072, 1024, 1024, 1024, 0, 0, 0, 0, 0, 0, 0, 1);
    // 4) PSIG[n][q][k] = sigmoid(CLAMP * tanh(xqa_q . xk_k)) -> fp16
    mfma_nt<128, 128, 1><<<dim3(8, 4, 64), blk, 0, stream>>>(
        XQAQ, XK, PSIG, nullptr, 64, 2048, 1024, 1024,
        512L * 2048, 64, 1024L * 1024, 64, 8388608L, 524288L, 16);

    // 5) two 256-q chunks: DP -> fused attention (scores+softmax+PV)
    for (int c = 0; c < 2; ++c) {
        mono_dp_k<<<dim3(64), dim3(256), 0, stream>>>(PSIG, ALPHAC, STATE, c * 256);
        fused_attn_k<<<dim3(64, 16, 1), blk, 0, stream>>>(
            XQAQ, XK, VT, ALPHAC, XO, c * 256);
    }

    // 6) out = XO @ ow^T + ob  (f32)
    mfma_nt<128, 128, 3><<<dim3(8, 16, 1), blk, 0, stream>>>(
        XO, OWBF, out, ob, 1024, 1024, 1024, 1024, 0, 0, 0, 0, 0, 0, 1);
}